// Round 10
// baseline (516.750 us; speedup 1.0000x reference)
//
#include <hip/hip_runtime.h>
#include <math.h>

#define NU 100000
#define NI 100000
#define NE 200000
#define NTOT (NU + NI)
#define NN 100000
#define NB_SCAN ((NN + 1023) / 1024)   // 98

typedef __bf16 bf16x8 __attribute__((ext_vector_type(8)));
typedef float f32x4 __attribute__((ext_vector_type(4)));
typedef uint ui32x4 __attribute__((ext_vector_type(4)));
#define MFMA(a, b, c) __builtin_amdgcn_mfma_f32_16x16x32_bf16(a, b, c, 0, 0, 0)

__device__ __forceinline__ ushort f2bf(float f) {
    uint u = __float_as_uint(f);
    return (ushort)((u + 0x7FFFu + ((u >> 16) & 1u)) >> 16);
}
__device__ __forceinline__ float bf2f(ushort h) {
    return __uint_as_float(((uint)h) << 16);
}
// packed bf16 convert: lo16 = bf16(a), hi16 = bf16(b)
__device__ __forceinline__ uint pk_bf16(float a, float b) {
    uint r;
    asm("v_cvt_pk_bf16_f32 %0, %1, %2" : "=v"(r) : "v"(a), "v"(b));
    return r;
}
__device__ __forceinline__ float fsig(float x) { return 1.f / (1.f + __expf(-x)); }
__device__ __forceinline__ float ftanh(float x) { return 1.f - 2.f / (1.f + __expf(2.f * x)); }

struct Ptr4 { const int* p[4]; };
struct PackW { const float* w[9]; };
struct GPair {
    const ushort* YA; const ushort* YB;
    const int* rpA; const int* colA; const float* rsdA;
    const int* rpB; const int* colB; const float* rsdB;
    const float* bA; const float* bB;
};

// ---------------- histogram: rels 0-3 = dst counts, 4-7 = src counts ----------------
__global__ void hist8_kernel(Ptr4 src, Ptr4 dst, int* __restrict__ cnt) {
    int e = blockIdx.x * blockDim.x + threadIdx.x;
    int r = blockIdx.y;
    if (e < NE) {
        const int* idx = (r < 4) ? dst.p[r] : src.p[r - 4];
        atomicAdd(&cnt[r * NN + idx[e]], 1);
    }
}

__global__ void rsqrt_int_kernel(const int* __restrict__ cnt, float* __restrict__ rs, int n) {
    int t = blockIdx.x * blockDim.x + threadIdx.x;
    if (t < n) rs[t] = rsqrtf(fmaxf((float)cnt[t], 1.0f));
}

// ---------------- exclusive scan (3-phase) over NN ints x 4 rels ----------------
__global__ __launch_bounds__(256) void scan_phase_a(const int* __restrict__ in, int* __restrict__ part) {
    __shared__ int sh[256];
    int rel = blockIdx.y;
    const int* inp = in + rel * NN;
    int tid = threadIdx.x;
    int base = blockIdx.x * 1024 + tid * 4;
    int s = 0;
#pragma unroll
    for (int i = 0; i < 4; i++) { int idx = base + i; if (idx < NN) s += inp[idx]; }
    sh[tid] = s; __syncthreads();
    for (int off = 128; off > 0; off >>= 1) {
        if (tid < off) sh[tid] += sh[tid + off];
        __syncthreads();
    }
    if (tid == 0) part[rel * 128 + blockIdx.x] = sh[0];
}

__global__ void scan_phase_b(int* __restrict__ part) {
    __shared__ int sh[128];
    int rel = blockIdx.x;
    int tid = threadIdx.x;
    int v = (tid < NB_SCAN) ? part[rel * 128 + tid] : 0;
    sh[tid] = v; __syncthreads();
    for (int off = 1; off < 128; off <<= 1) {
        int t = (tid >= off) ? sh[tid - off] : 0;
        __syncthreads();
        sh[tid] += t;
        __syncthreads();
    }
    if (tid < NB_SCAN) part[rel * 128 + tid] = sh[tid] - v;   // exclusive
}

__global__ __launch_bounds__(256) void scan_phase_c(int* __restrict__ cnt, const int* __restrict__ part,
                                                    int* __restrict__ row_ptr, float* __restrict__ rs) {
    __shared__ int sh[256];
    int rel = blockIdx.y;
    int* inp = cnt + rel * NN;
    int* rp = row_ptr + rel * (NN + 1);
    float* rsd = rs + rel * NN;
    int tid = threadIdx.x;
    int base = blockIdx.x * 1024 + tid * 4;
    int v[4]; int s = 0;
#pragma unroll
    for (int i = 0; i < 4; i++) { int idx = base + i; v[i] = (idx < NN) ? inp[idx] : 0; s += v[i]; }
    sh[tid] = s; __syncthreads();
    for (int off = 1; off < 256; off <<= 1) {
        int t = (tid >= off) ? sh[tid - off] : 0;
        __syncthreads();
        sh[tid] += t;
        __syncthreads();
    }
    int excl = sh[tid] - s + part[rel * 128 + blockIdx.x];
#pragma unroll
    for (int i = 0; i < 4; i++) {
        int idx = base + i;
        if (idx < NN) {
            rp[idx] = excl;
            inp[idx] = excl;                     // cursor init
            rsd[idx] = rsqrtf(fmaxf((float)v[i], 1.0f));
            excl += v[i];
        }
    }
    if (blockIdx.x == 0 && tid == 0) rp[NN] = NE;
}

__global__ void fill4_kernel(Ptr4 src, Ptr4 dst, int* __restrict__ cursor, int* __restrict__ col) {
    int e = blockIdx.x * blockDim.x + threadIdx.x;
    int r = blockIdx.y;
    if (e >= NE) return;
    int s = src.p[r][e], d = dst.p[r][e];
    int p = atomicAdd(&cursor[r * NN + d], 1);
    col[(size_t)r * NE + p] = s;
}

// ---------------- weight pack (split hi/lo, MFMA B-fragment order) ----------------
// pack[((nf*4 + ks)*64 + l)*8 + j] = B[ks*32 + (l>>4)*8 + j][nf*16 + (l&15)]
__global__ void pack_all_kernel(PackW pw, ushort* __restrict__ hi, ushort* __restrict__ lo) {
    int tid = blockIdx.x * blockDim.x + threadIdx.x;
    int wi, local, N, trans;
    if (tid < 8 * 16384) { wi = tid >> 14; local = tid & 16383; N = 128; trans = 0; }
    else {
        int t = tid - 8 * 16384;
        if (t >= 49152) return;
        wi = 8; local = t; N = 384; trans = 1;
    }
    int j = local & 7;
    int l = (local >> 3) & 63;
    int ks = (local >> 9) & 3;
    int nf = local >> 11;
    int k = ks * 32 + ((l >> 4) << 3) + j;
    int n = nf * 16 + (l & 15);
    const float* W = pw.w[wi];
    float v = trans ? W[(size_t)n * 128 + k] : W[(size_t)k * N + n];
    size_t d = (size_t)wi * 16384 + local;
    ushort h = f2bf(v);
    hi[d] = h;
    lo[d] = f2bf(v - bf2f(h));
}

// ---------------- transform: Y[2y+o] = rs_src[rel] * (feats(y) @ W1[2y+o]), bf16 out ----------------
// split-A x split-W (3 MFMA): near-fp32 product, one bf16 rounding at store.
__global__ __launch_bounds__(512) void transform_kernel(
    const float* __restrict__ xu, const float* __restrict__ xi,
    const ushort* __restrict__ pk_h, const ushort* __restrict__ pk_l,
    const float* __restrict__ rs_src, ushort* __restrict__ Y) {
    __shared__ __align__(16) ushort Ah[64 * 128];
    __shared__ __align__(16) ushort Al[64 * 128];
    const int y = blockIdx.y;
    const float* x = y ? xi : xu;
    const int tid = threadIdx.x;
    const int row0 = blockIdx.x * 64;

    {
        const int r = tid >> 3, q = tid & 7;
        const int gr = row0 + r;
        const f32x4* xp = (const f32x4*)(x + (size_t)gr * 128 + q * 16);
#pragma unroll
        for (int k = 0; k < 4; ++k) {
            f32x4 v = (gr < NN) ? xp[k] : (f32x4)(0.f);
            ushort4 h4, l4;
            h4.x = f2bf(v[0]); l4.x = f2bf(v[0] - bf2f(h4.x));
            h4.y = f2bf(v[1]); l4.y = f2bf(v[1] - bf2f(h4.y));
            h4.z = f2bf(v[2]); l4.z = f2bf(v[2] - bf2f(h4.z));
            h4.w = f2bf(v[3]); l4.w = f2bf(v[3] - bf2f(h4.w));
            int base = (r * 128 + q * 16 + k * 4) ^ ((r & 7) << 3);
            *reinterpret_cast<ushort4*>(&Ah[base]) = h4;
            *reinterpret_cast<ushort4*>(&Al[base]) = l4;
        }
    }
    __syncthreads();

    const int wv = tid >> 6, l = tid & 63;
    const int l15 = l & 15, lh = l >> 4;
    const int rh = wv >> 2, np = wv & 3;

    f32x4 acc[2][2][2];   // [o][m][nfi]
#pragma unroll
    for (int o = 0; o < 2; o++)
#pragma unroll
        for (int m = 0; m < 2; m++)
#pragma unroll
            for (int nfi = 0; nfi < 2; nfi++) acc[o][m][nfi] = (f32x4)(0.f);

#pragma unroll
    for (int ks = 0; ks < 4; ++ks) {
        bf16x8 aH[2], aL[2];
#pragma unroll
        for (int m = 0; m < 2; ++m) {
            int row = rh * 32 + m * 16 + l15;
            int idx = (row * 128 + ks * 32 + lh * 8) ^ ((row & 7) << 3);
            aH[m] = *reinterpret_cast<const bf16x8*>(&Ah[idx]);
            aL[m] = *reinterpret_cast<const bf16x8*>(&Al[idx]);
        }
#pragma unroll
        for (int o = 0; o < 2; ++o) {
            const ushort* wh = pk_h + (size_t)(2 * y + o) * 16384;
            const ushort* wl = pk_l + (size_t)(2 * y + o) * 16384;
#pragma unroll
            for (int nfi = 0; nfi < 2; ++nfi) {
                int nf = np * 2 + nfi;
                size_t off = ((size_t)(nf * 4 + ks) * 64 + l) * 8;
                bf16x8 bH = *reinterpret_cast<const bf16x8*>(wh + off);
                bf16x8 bL = *reinterpret_cast<const bf16x8*>(wl + off);
#pragma unroll
                for (int m = 0; m < 2; ++m) {
                    acc[o][m][nfi] = MFMA(aH[m], bH, acc[o][m][nfi]);
                    acc[o][m][nfi] = MFMA(aL[m], bH, acc[o][m][nfi]);
                    acc[o][m][nfi] = MFMA(aH[m], bL, acc[o][m][nfi]);
                }
            }
        }
    }

    // ---- epilogue: scale by rs_src[rel], pair cols via shfl, packed u32 stores ----
    const bool ev = (l15 & 1) == 0;
    const int ia = ev ? 0 : 2;
#pragma unroll
    for (int o = 0; o < 2; ++o) {
        int slot = 2 * y + o;
        uint* Yo32 = (uint*)(Y + (size_t)slot * ((size_t)NN * 128));
        const float* rs = rs_src + slot * NN;
#pragma unroll
        for (int m = 0; m < 2; ++m) {
            int rbase = row0 + rh * 32 + m * 16 + lh * 4;
#pragma unroll
            for (int nfi = 0; nfi < 2; ++nfi) {
                int c = (np * 2 + nfi) * 16 + l15;
                int cb2 = (c & ~1) >> 1;
                float v[4], p[4];
#pragma unroll
                for (int i = 0; i < 4; ++i) {
                    int gri = rbase + i; if (gri > NN - 1) gri = NN - 1;
                    v[i] = acc[o][m][nfi][i] * rs[gri];
                }
#pragma unroll
                for (int i = 0; i < 4; ++i) p[i] = __shfl_xor(v[i], 1);
#pragma unroll
                for (int t = 0; t < 2; ++t) {
                    int i = ia + t, gr = rbase + i;
                    if (gr < NN)
                        Yo32[(size_t)gr * 64 + cb2] = ev ? pk_bf16(v[i], p[i]) : pk_bf16(p[i], v[i]);
                }
            }
        }
    }
}

// ---------------- merged dual gather: out[d] = rsdA*sum(YA[s]) + rsdB*sum(YB[s]) + bA + bB ----------------
// Y rows are pre-scaled by rs_src. One wave per dst row; lane owns cols 2l, 2l+1.
template <bool OUT_BF16>
__global__ __launch_bounds__(256) void gather2_kernel(GPair g0, GPair g1,
                                                      uint* __restrict__ ob0, uint* __restrict__ ob1,
                                                      float* __restrict__ of0, float* __restrict__ of1) {
    const GPair G = blockIdx.y ? g1 : g0;
    const int d = blockIdx.x * 4 + (threadIdx.x >> 6);
    const int lane = threadIdx.x & 63;
    float a0 = 0.f, a1 = 0.f, b0 = 0.f, b1 = 0.f;
    {
        int j0 = G.rpA[d], j1 = G.rpA[d + 1];
        int j = j0;
        for (; j + 2 <= j1; j += 2) {
            int s0 = G.colA[j], s1 = G.colA[j + 1];
            uint u0 = ((const uint*)(G.YA + (size_t)s0 * 128))[lane];
            uint u1 = ((const uint*)(G.YA + (size_t)s1 * 128))[lane];
            a0 += __uint_as_float(u0 << 16); a1 += __uint_as_float(u0 & 0xffff0000u);
            a0 += __uint_as_float(u1 << 16); a1 += __uint_as_float(u1 & 0xffff0000u);
        }
        if (j < j1) {
            int s0 = G.colA[j];
            uint u0 = ((const uint*)(G.YA + (size_t)s0 * 128))[lane];
            a0 += __uint_as_float(u0 << 16); a1 += __uint_as_float(u0 & 0xffff0000u);
        }
    }
    {
        int j0 = G.rpB[d], j1 = G.rpB[d + 1];
        int j = j0;
        for (; j + 2 <= j1; j += 2) {
            int s0 = G.colB[j], s1 = G.colB[j + 1];
            uint u0 = ((const uint*)(G.YB + (size_t)s0 * 128))[lane];
            uint u1 = ((const uint*)(G.YB + (size_t)s1 * 128))[lane];
            b0 += __uint_as_float(u0 << 16); b1 += __uint_as_float(u0 & 0xffff0000u);
            b0 += __uint_as_float(u1 << 16); b1 += __uint_as_float(u1 & 0xffff0000u);
        }
        if (j < j1) {
            int s0 = G.colB[j];
            uint u0 = ((const uint*)(G.YB + (size_t)s0 * 128))[lane];
            b0 += __uint_as_float(u0 << 16); b1 += __uint_as_float(u0 & 0xffff0000u);
        }
    }
    float rA = G.rsdA[d], rB = G.rsdB[d];
    int c = lane * 2;
    float v0 = fmaf(a0, rA, fmaf(b0, rB, G.bA[c] + G.bB[c]));
    float v1 = fmaf(a1, rA, fmaf(b1, rB, G.bA[c + 1] + G.bB[c + 1]));
    if (OUT_BF16) {
        uint* o = blockIdx.y ? ob1 : ob0;
        o[(size_t)d * 64 + lane] = pk_bf16(v0, v1);
    } else {
        float* o = blockIdx.y ? of1 : of0;
        *reinterpret_cast<float2*>(o + (size_t)d * 128 + c) = make_float2(v0, v1);
    }
}

// ---------------- GRU + layer-2 transform: h = gru(relu(hcpre)); Z[2y+o] = rs_src*(h @ W2[2y+o]) ----------------
__global__ __launch_bounds__(512) void gruz_kernel(
    const ushort* __restrict__ hcpre,
    const ushort* __restrict__ pk_h, const ushort* __restrict__ pk_l,
    const float* __restrict__ bih, const float* __restrict__ bhh,
    const float* __restrict__ rs_src, ushort* __restrict__ Z) {
    __shared__ __align__(16) ushort Xh[64 * 128];
    __shared__ __align__(16) ushort Hh[64 * 128];
    const int y = blockIdx.y;
    const ushort* xs = hcpre + (size_t)y * NU * 128;
    const int tid = threadIdx.x;
    const int row0 = blockIdx.x * 64;

    // ---- stage relu(x): x already bf16 -> exact staging (relu via sign test) ----
    {
        const int r = tid >> 3, q = tid & 7;
        const int gr = row0 + r;
        const ui32x4* xp = (const ui32x4*)(xs + (size_t)gr * 128 + q * 16);
#pragma unroll
        for (int k = 0; k < 2; ++k) {
            ui32x4 v = (gr < NN) ? xp[k] : (ui32x4)(0u);
#pragma unroll
            for (int t = 0; t < 4; ++t) {
                uint u = v[t];
                uint lo = (u & 0x8000u) ? 0u : (u & 0xFFFFu);
                uint hi = (u & 0x80000000u) ? 0u : (u & 0xFFFF0000u);
                v[t] = lo | hi;
            }
            int base = (r * 128 + q * 16 + k * 8) ^ ((r & 7) << 3);
            *reinterpret_cast<ui32x4*>(&Xh[base]) = v;
        }
    }
    __syncthreads();

    const int wv = tid >> 6, l = tid & 63;
    const int l15 = l & 15, lh = l >> 4;
    const int rh = wv >> 2, np = wv & 3;
    const ushort* gwh = pk_h + (size_t)8 * 16384;
    const ushort* gwl = pk_l + (size_t)8 * 16384;

    // ---- GRU gates GEMM: gi = x @ wih^T (split-W) ----
    f32x4 g3[3][2][2];
#pragma unroll
    for (int g = 0; g < 3; g++)
#pragma unroll
        for (int m = 0; m < 2; m++)
#pragma unroll
            for (int nfi = 0; nfi < 2; nfi++) g3[g][m][nfi] = (f32x4)(0.f);

#pragma unroll
    for (int ks = 0; ks < 4; ++ks) {
        bf16x8 aH[2];
#pragma unroll
        for (int m = 0; m < 2; ++m) {
            int row = rh * 32 + m * 16 + l15;
            int idx = (row * 128 + ks * 32 + lh * 8) ^ ((row & 7) << 3);
            aH[m] = *reinterpret_cast<const bf16x8*>(&Xh[idx]);
        }
#pragma unroll
        for (int g = 0; g < 3; ++g) {
#pragma unroll
            for (int nfi = 0; nfi < 2; ++nfi) {
                int gnf = g * 8 + np * 2 + nfi;
                size_t off = ((size_t)(gnf * 4 + ks) * 64 + l) * 8;
                bf16x8 bH = *reinterpret_cast<const bf16x8*>(gwh + off);
                bf16x8 bL = *reinterpret_cast<const bf16x8*>(gwl + off);
#pragma unroll
                for (int m = 0; m < 2; ++m) {
                    g3[g][m][nfi] = MFMA(aH[m], bH, g3[g][m][nfi]);
                    g3[g][m][nfi] = MFMA(aH[m], bL, g3[g][m][nfi]);
                }
            }
        }
    }

    // ---- gates (gh = bhh, h0 = 0); stage h bf16 into Hh ----
#pragma unroll
    for (int nfi = 0; nfi < 2; ++nfi) {
        int c = (np * 2 + nfi) * 16 + l15;
        float b0 = bih[c] + bhh[c];
        float b1 = bih[128 + c] + bhh[128 + c];
        float b2i = bih[256 + c], b2h = bhh[256 + c];
#pragma unroll
        for (int m = 0; m < 2; ++m) {
#pragma unroll
            for (int i = 0; i < 4; ++i) {
                int rr = rh * 32 + m * 16 + lh * 4 + i;
                float rg = fsig(g3[0][m][nfi][i] + b0);
                float zz = fsig(g3[1][m][nfi][i] + b1);
                float nn = ftanh(g3[2][m][nfi][i] + b2i + rg * b2h);
                Hh[(rr * 128 + c) ^ ((rr & 7) << 3)] = f2bf((1.f - zz) * nn);
            }
        }
    }
    __syncthreads();

    // ---- Z GEMMs: Z[2y+o] = h @ W2[2y+o] (split-W) ----
    f32x4 za[2][2][2];
#pragma unroll
    for (int o = 0; o < 2; o++)
#pragma unroll
        for (int m = 0; m < 2; m++)
#pragma unroll
            for (int nfi = 0; nfi < 2; nfi++) za[o][m][nfi] = (f32x4)(0.f);

#pragma unroll
    for (int ks = 0; ks < 4; ++ks) {
        bf16x8 aH[2];
#pragma unroll
        for (int m = 0; m < 2; ++m) {
            int row = rh * 32 + m * 16 + l15;
            int idx = (row * 128 + ks * 32 + lh * 8) ^ ((row & 7) << 3);
            aH[m] = *reinterpret_cast<const bf16x8*>(&Hh[idx]);
        }
#pragma unroll
        for (int o = 0; o < 2; ++o) {
            const ushort* wh = pk_h + (size_t)(4 + 2 * y + o) * 16384;
            const ushort* wl = pk_l + (size_t)(4 + 2 * y + o) * 16384;
#pragma unroll
            for (int nfi = 0; nfi < 2; ++nfi) {
                int nf = np * 2 + nfi;
                size_t off = ((size_t)(nf * 4 + ks) * 64 + l) * 8;
                bf16x8 bH = *reinterpret_cast<const bf16x8*>(wh + off);
                bf16x8 bL = *reinterpret_cast<const bf16x8*>(wl + off);
#pragma unroll
                for (int m = 0; m < 2; ++m) {
                    za[o][m][nfi] = MFMA(aH[m], bH, za[o][m][nfi]);
                    za[o][m][nfi] = MFMA(aH[m], bL, za[o][m][nfi]);
                }
            }
        }
    }

    // ---- epilogue: scale by rs_src[rel], paired packed u32 stores ----
    const bool ev = (l15 & 1) == 0;
    const int ia = ev ? 0 : 2;
#pragma unroll
    for (int o = 0; o < 2; ++o) {
        int slot = 2 * y + o;
        uint* Zo32 = (uint*)(Z + (size_t)slot * ((size_t)NN * 128));
        const float* rs = rs_src + slot * NN;
#pragma unroll
        for (int m = 0; m < 2; ++m) {
            int rbase = row0 + rh * 32 + m * 16 + lh * 4;
#pragma unroll
            for (int nfi = 0; nfi < 2; ++nfi) {
                int c = (np * 2 + nfi) * 16 + l15;
                int cb2 = (c & ~1) >> 1;
                float v[4], p[4];
#pragma unroll
                for (int i = 0; i < 4; ++i) {
                    int gri = rbase + i; if (gri > NN - 1) gri = NN - 1;
                    v[i] = za[o][m][nfi][i] * rs[gri];
                }
#pragma unroll
                for (int i = 0; i < 4; ++i) p[i] = __shfl_xor(v[i], 1);
#pragma unroll
                for (int t = 0; t < 2; ++t) {
                    int i = ia + t, gr = rbase + i;
                    if (gr < NN)
                        Zo32[(size_t)gr * 64 + cb2] = ev ? pk_bf16(v[i], p[i]) : pk_bf16(p[i], v[i]);
                }
            }
        }
    }
}

// ---------------- launch ----------------
extern "C" void kernel_launch(void* const* d_in, const int* in_sizes, int n_in,
                              void* d_out, int out_size, void* d_ws, size_t ws_size,
                              hipStream_t stream) {
    const float* feat_user = (const float*)d_in[0];
    const float* feat_item = (const float*)d_in[1];

    // relation order: 0=follows(U->U) 1=buys(U->I) 2=revbuys(I->U) 3=similar(I->I)
    Ptr4 srcs = {{(const int*)d_in[3], (const int*)d_in[9], (const int*)d_in[15], (const int*)d_in[21]}};
    Ptr4 dsts = {{(const int*)d_in[4], (const int*)d_in[10], (const int*)d_in[16], (const int*)d_in[22]}};
    const float* b1[4] = {(const float*)d_in[6],  (const float*)d_in[12], (const float*)d_in[18], (const float*)d_in[24]};
    const float* b2[4] = {(const float*)d_in[8],  (const float*)d_in[14], (const float*)d_in[20], (const float*)d_in[26]};

    PackW pw = {{(const float*)d_in[5], (const float*)d_in[11], (const float*)d_in[17], (const float*)d_in[23],
                 (const float*)d_in[7], (const float*)d_in[13], (const float*)d_in[19], (const float*)d_in[25],
                 (const float*)d_in[27]}};
    const float* bih = (const float*)d_in[29];
    const float* bhh = (const float*)d_in[30];

    // ---- workspace ----
    char* w = (char*)d_ws;
    auto alloc = [&](size_t bytes) { char* r = w; w += (bytes + 255) & ~(size_t)255; return r; };
    int* cnt8         = (int*)alloc(8 * NN * sizeof(int));
    float* rs_src_all = (float*)alloc(4 * NN * sizeof(float));
    float* rs_dst_all = (float*)alloc(4 * NN * sizeof(float));
    int* row_ptr_all  = (int*)alloc(4 * (NN + 1) * sizeof(int));
    int* col_all      = (int*)alloc((size_t)4 * NE * sizeof(int));
    int* part         = (int*)alloc(4 * 128 * sizeof(int));
    ushort* pkh_all   = (ushort*)alloc((size_t)(8 * 16384 + 49152) * sizeof(ushort));
    ushort* pkl_all   = (ushort*)alloc((size_t)(8 * 16384 + 49152) * sizeof(ushort));
    ushort* Ybuf      = (ushort*)alloc((size_t)4 * NN * 128 * sizeof(ushort));  // Y then Z (reused)

    float* outLo = (float*)d_out;
    float* outHi = outLo + (size_t)NU * 128;
    ushort* hcpre = (ushort*)d_out;          // bf16 scratch in d_out (overwritten by final gathers)

    const int EB = (NE + 255) / 256;

    // ---- CSR build ----
    hipMemsetAsync(cnt8, 0, 8 * NN * sizeof(int), stream);
    hist8_kernel<<<dim3(EB, 8), 256, 0, stream>>>(srcs, dsts, cnt8);
    scan_phase_a<<<dim3(NB_SCAN, 4), 256, 0, stream>>>(cnt8, part);
    scan_phase_b<<<4, 128, 0, stream>>>(part);
    scan_phase_c<<<dim3(NB_SCAN, 4), 256, 0, stream>>>(cnt8, part, row_ptr_all, rs_dst_all);
    rsqrt_int_kernel<<<(4 * NN + 255) / 256, 256, 0, stream>>>(cnt8 + 4 * NN, rs_src_all, 4 * NN);
    fill4_kernel<<<dim3(EB, 4), 256, 0, stream>>>(srcs, dsts, cnt8, col_all);

    // ---- pack weights ----
    pack_all_kernel<<<(8 * 16384 + 49152 + 255) / 256, 256, 0, stream>>>(pw, pkh_all, pkl_all);

    const int GB = (NN + 63) / 64;   // 1563
    const int GGB = NN / 4;          // 25000 (4 rows/block)

    auto RP = [&](int r) { return row_ptr_all + r * (NN + 1); };
    auto CL = [&](int r) { return col_all + (size_t)r * NE; };
    auto RD = [&](int r) { return rs_dst_all + r * NN; };
    auto YS = [&](int s) { return (const ushort*)(Ybuf + (size_t)s * NN * 128); };

    // ---- layer-1 transform: Y[0]=fu@W1f Y[1]=fu@W1b Y[2]=fi@W1r Y[3]=fi@W1s (rs_src-scaled) ----
    transform_kernel<<<dim3(GB, 2), 512, 0, stream>>>(feat_user, feat_item, pkh_all, pkl_all,
                                                      rs_src_all, Ybuf);

    // ---- layer-1 gathers (merged) -> hc_pre (bf16, in d_out scratch) ----
    {
        GPair gy0 = {YS(0), YS(2), RP(0), CL(0), RD(0), RP(2), CL(2), RD(2), b1[0], b1[2]};
        GPair gy1 = {YS(1), YS(3), RP(1), CL(1), RD(1), RP(3), CL(3), RD(3), b1[1], b1[3]};
        gather2_kernel<true><<<dim3(GGB, 2), 256, 0, stream>>>(
            gy0, gy1, (uint*)hcpre, (uint*)(hcpre + (size_t)NU * 128), nullptr, nullptr);
    }

    // ---- GRU + layer-2 transform: Z[0]=hu@W2f Z[1]=hu@W2b Z[2]=hi@W2r Z[3]=hi@W2s (rs_src-scaled) ----
    gruz_kernel<<<dim3(GB, 2), 512, 0, stream>>>(hcpre, pkh_all, pkl_all, bih, bhh, rs_src_all, Ybuf);

    // ---- layer-2 gathers (merged) -> d_out (fp32) ----
    {
        GPair gy0 = {YS(0), YS(2), RP(0), CL(0), RD(0), RP(2), CL(2), RD(2), b2[0], b2[2]};
        GPair gy1 = {YS(1), YS(3), RP(1), CL(1), RD(1), RP(3), CL(3), RD(3), b2[1], b2[3]};
        gather2_kernel<false><<<dim3(GGB, 2), 256, 0, stream>>>(
            gy0, gy1, nullptr, nullptr, outLo, outHi);
    }
}

// Round 11
// 483.561 us; speedup vs baseline: 1.0686x; 1.0686x over previous
//
#include <hip/hip_runtime.h>
#include <math.h>

#define NU 100000
#define NI 100000
#define NE 200000
#define NTOT (NU + NI)
#define NN 100000
#define NB_SCAN ((NN + 1023) / 1024)   // 98

typedef __bf16 bf16x8 __attribute__((ext_vector_type(8)));
typedef float f32x4 __attribute__((ext_vector_type(4)));
typedef uint ui32x4 __attribute__((ext_vector_type(4)));
#define MFMA(a, b, c) __builtin_amdgcn_mfma_f32_16x16x32_bf16(a, b, c, 0, 0, 0)

__device__ __forceinline__ ushort f2bf(float f) {
    uint u = __float_as_uint(f);
    return (ushort)((u + 0x7FFFu + ((u >> 16) & 1u)) >> 16);
}
__device__ __forceinline__ float bf2f(ushort h) {
    return __uint_as_float(((uint)h) << 16);
}
// packed bf16 convert (single VALU op): lo16 = bf16(a), hi16 = bf16(b), RNE
__device__ __forceinline__ uint pk_bf16(float a, float b) {
    uint r;
    asm("v_cvt_pk_bf16_f32 %0, %1, %2" : "=v"(r) : "v"(a), "v"(b));
    return r;
}
// single-value bf16 via cvt_pk (1 op vs ~5 for software round)
__device__ __forceinline__ ushort f2bf1(float a) { return (ushort)(pk_bf16(a, a) & 0xffffu); }
__device__ __forceinline__ float fsig(float x) { return 1.f / (1.f + __expf(-x)); }
__device__ __forceinline__ float ftanh(float x) { return 1.f - 2.f / (1.f + __expf(2.f * x)); }

struct Ptr4 { const int* p[4]; };
struct PackW { const float* w[9]; };
struct GPair {
    const ushort* YA; const ushort* YB;
    const int* rpA; const int2* eA; const float* rsdA;
    const int* rpB; const int2* eB; const float* rsdB;
    const float* bA; const float* bB;
};

// ---------------- histogram: rels 0-3 = dst counts, 4-7 = src counts ----------------
__global__ void hist8_kernel(Ptr4 src, Ptr4 dst, int* __restrict__ cnt) {
    int e = blockIdx.x * blockDim.x + threadIdx.x;
    int r = blockIdx.y;
    if (e < NE) {
        const int* idx = (r < 4) ? dst.p[r] : src.p[r - 4];
        atomicAdd(&cnt[r * NN + idx[e]], 1);
    }
}

__global__ void rsqrt_int_kernel(const int* __restrict__ cnt, float* __restrict__ rs, int n) {
    int t = blockIdx.x * blockDim.x + threadIdx.x;
    if (t < n) rs[t] = rsqrtf(fmaxf((float)cnt[t], 1.0f));
}

// ---------------- exclusive scan (3-phase) over NN ints x 4 rels ----------------
__global__ __launch_bounds__(256) void scan_phase_a(const int* __restrict__ in, int* __restrict__ part) {
    __shared__ int sh[256];
    int rel = blockIdx.y;
    const int* inp = in + rel * NN;
    int tid = threadIdx.x;
    int base = blockIdx.x * 1024 + tid * 4;
    int s = 0;
#pragma unroll
    for (int i = 0; i < 4; i++) { int idx = base + i; if (idx < NN) s += inp[idx]; }
    sh[tid] = s; __syncthreads();
    for (int off = 128; off > 0; off >>= 1) {
        if (tid < off) sh[tid] += sh[tid + off];
        __syncthreads();
    }
    if (tid == 0) part[rel * 128 + blockIdx.x] = sh[0];
}

__global__ void scan_phase_b(int* __restrict__ part) {
    __shared__ int sh[128];
    int rel = blockIdx.x;
    int tid = threadIdx.x;
    int v = (tid < NB_SCAN) ? part[rel * 128 + tid] : 0;
    sh[tid] = v; __syncthreads();
    for (int off = 1; off < 128; off <<= 1) {
        int t = (tid >= off) ? sh[tid - off] : 0;
        __syncthreads();
        sh[tid] += t;
        __syncthreads();
    }
    if (tid < NB_SCAN) part[rel * 128 + tid] = sh[tid] - v;   // exclusive
}

__global__ __launch_bounds__(256) void scan_phase_c(int* __restrict__ cnt, const int* __restrict__ part,
                                                    int* __restrict__ row_ptr, float* __restrict__ rs) {
    __shared__ int sh[256];
    int rel = blockIdx.y;
    int* inp = cnt + rel * NN;
    int* rp = row_ptr + rel * (NN + 1);
    float* rsd = rs + rel * NN;
    int tid = threadIdx.x;
    int base = blockIdx.x * 1024 + tid * 4;
    int v[4]; int s = 0;
#pragma unroll
    for (int i = 0; i < 4; i++) { int idx = base + i; v[i] = (idx < NN) ? inp[idx] : 0; s += v[i]; }
    sh[tid] = s; __syncthreads();
    for (int off = 1; off < 256; off <<= 1) {
        int t = (tid >= off) ? sh[tid - off] : 0;
        __syncthreads();
        sh[tid] += t;
        __syncthreads();
    }
    int excl = sh[tid] - s + part[rel * 128 + blockIdx.x];
#pragma unroll
    for (int i = 0; i < 4; i++) {
        int idx = base + i;
        if (idx < NN) {
            rp[idx] = excl;
            inp[idx] = excl;                     // cursor init
            rsd[idx] = rsqrtf(fmaxf((float)v[i], 1.0f));
            excl += v[i];
        }
    }
    if (blockIdx.x == 0 && tid == 0) rp[NN] = NE;
}

__global__ void fill4_kernel(Ptr4 src, Ptr4 dst, const float* __restrict__ rs_src,
                             int* __restrict__ cursor, int2* __restrict__ edge) {
    int e = blockIdx.x * blockDim.x + threadIdx.x;
    int r = blockIdx.y;
    if (e >= NE) return;
    int s = src.p[r][e], d = dst.p[r][e];
    int p = atomicAdd(&cursor[r * NN + d], 1);
    edge[(size_t)r * NE + p] = make_int2(s, __float_as_int(rs_src[r * NN + s]));
}

// ---------------- weight pack (split hi/lo, MFMA B-fragment order) ----------------
// pack[((nf*4 + ks)*64 + l)*8 + j] = B[ks*32 + (l>>4)*8 + j][nf*16 + (l&15)]
__global__ void pack_all_kernel(PackW pw, ushort* __restrict__ hi, ushort* __restrict__ lo) {
    int tid = blockIdx.x * blockDim.x + threadIdx.x;
    int wi, local, N, trans;
    if (tid < 8 * 16384) { wi = tid >> 14; local = tid & 16383; N = 128; trans = 0; }
    else {
        int t = tid - 8 * 16384;
        if (t >= 49152) return;
        wi = 8; local = t; N = 384; trans = 1;
    }
    int j = local & 7;
    int l = (local >> 3) & 63;
    int ks = (local >> 9) & 3;
    int nf = local >> 11;
    int k = ks * 32 + ((l >> 4) << 3) + j;
    int n = nf * 16 + (l & 15);
    const float* W = pw.w[wi];
    float v = trans ? W[(size_t)n * 128 + k] : W[(size_t)k * N + n];
    size_t d = (size_t)wi * 16384 + local;
    ushort h = f2bf(v);
    hi[d] = h;
    lo[d] = f2bf(v - bf2f(h));
}

// ---------------- transform: Y[2y+o] = feats(y) @ W1[2y+o], bf16 out ----------------
// split-A x split-W (3 MFMA): near-fp32 product, one bf16 rounding at store.
__global__ __launch_bounds__(512) void transform_kernel(
    const float* __restrict__ xu, const float* __restrict__ xi,
    const ushort* __restrict__ pk_h, const ushort* __restrict__ pk_l,
    ushort* __restrict__ Y) {
    __shared__ __align__(16) ushort Ah[64 * 128];
    __shared__ __align__(16) ushort Al[64 * 128];
    const int y = blockIdx.y;
    const float* x = y ? xi : xu;
    const int tid = threadIdx.x;
    const int row0 = blockIdx.x * 64;

    // ---- stage: fp32 -> split bf16 via cvt_pk pairs (12 ops / 4 elems) ----
    {
        const int r = tid >> 3, q = tid & 7;
        const int gr = row0 + r;
        const f32x4* xp = (const f32x4*)(x + (size_t)gr * 128 + q * 16);
#pragma unroll
        for (int k = 0; k < 4; ++k) {
            f32x4 v = (gr < NN) ? xp[k] : (f32x4)(0.f);
            uint h01 = pk_bf16(v[0], v[1]);
            uint h23 = pk_bf16(v[2], v[3]);
            float r0 = v[0] - __uint_as_float(h01 << 16);
            float r1 = v[1] - __uint_as_float(h01 & 0xffff0000u);
            float r2 = v[2] - __uint_as_float(h23 << 16);
            float r3 = v[3] - __uint_as_float(h23 & 0xffff0000u);
            uint l01 = pk_bf16(r0, r1);
            uint l23 = pk_bf16(r2, r3);
            int base = (r * 128 + q * 16 + k * 4) ^ ((r & 7) << 3);
            *reinterpret_cast<uint2*>(&Ah[base]) = make_uint2(h01, h23);
            *reinterpret_cast<uint2*>(&Al[base]) = make_uint2(l01, l23);
        }
    }
    __syncthreads();

    const int wv = tid >> 6, l = tid & 63;
    const int l15 = l & 15, lh = l >> 4;
    const int rh = wv >> 2, np = wv & 3;

    f32x4 acc[2][2][2];   // [o][m][nfi]
#pragma unroll
    for (int o = 0; o < 2; o++)
#pragma unroll
        for (int m = 0; m < 2; m++)
#pragma unroll
            for (int nfi = 0; nfi < 2; nfi++) acc[o][m][nfi] = (f32x4)(0.f);

#pragma unroll
    for (int ks = 0; ks < 4; ++ks) {
        bf16x8 aH[2], aL[2];
#pragma unroll
        for (int m = 0; m < 2; ++m) {
            int row = rh * 32 + m * 16 + l15;
            int idx = (row * 128 + ks * 32 + lh * 8) ^ ((row & 7) << 3);
            aH[m] = *reinterpret_cast<const bf16x8*>(&Ah[idx]);
            aL[m] = *reinterpret_cast<const bf16x8*>(&Al[idx]);
        }
#pragma unroll
        for (int o = 0; o < 2; ++o) {
            const ushort* wh = pk_h + (size_t)(2 * y + o) * 16384;
            const ushort* wl = pk_l + (size_t)(2 * y + o) * 16384;
#pragma unroll
            for (int nfi = 0; nfi < 2; ++nfi) {
                int nf = np * 2 + nfi;
                size_t off = ((size_t)(nf * 4 + ks) * 64 + l) * 8;
                bf16x8 bH = *reinterpret_cast<const bf16x8*>(wh + off);
                bf16x8 bL = *reinterpret_cast<const bf16x8*>(wl + off);
#pragma unroll
                for (int m = 0; m < 2; ++m) {
                    acc[o][m][nfi] = MFMA(aH[m], bH, acc[o][m][nfi]);
                    acc[o][m][nfi] = MFMA(aL[m], bH, acc[o][m][nfi]);
                    acc[o][m][nfi] = MFMA(aH[m], bL, acc[o][m][nfi]);
                }
            }
        }
    }

#pragma unroll
    for (int o = 0; o < 2; ++o) {
        ushort* Yo = Y + (size_t)(2 * y + o) * ((size_t)NN * 128);
#pragma unroll
        for (int m = 0; m < 2; ++m)
#pragma unroll
            for (int nfi = 0; nfi < 2; ++nfi) {
                int c = (np * 2 + nfi) * 16 + l15;
#pragma unroll
                for (int i = 0; i < 4; ++i) {
                    int gr = row0 + rh * 32 + m * 16 + lh * 4 + i;
                    if (gr < NN) Yo[(size_t)gr * 128 + c] = f2bf1(acc[o][m][nfi][i]);
                }
            }
    }
}

// ---------------- merged dual gather: out[d] = rsdA*sum(scl*YA[s]) + rsdB*sum(scl*YB[s]) + bA + bB ----------------
// one wave per dst row; lane owns cols 2l, 2l+1 (one uint of the bf16 row per edge).
template <bool OUT_BF16>
__global__ __launch_bounds__(256) void gather2_kernel(GPair g0, GPair g1,
                                                      uint* __restrict__ ob0, uint* __restrict__ ob1,
                                                      float* __restrict__ of0, float* __restrict__ of1) {
    const GPair G = blockIdx.y ? g1 : g0;
    const int d = blockIdx.x * 4 + (threadIdx.x >> 6);
    const int lane = threadIdx.x & 63;

    float a0 = 0.f, a1 = 0.f, b0 = 0.f, b1 = 0.f;
    {
        int j0 = G.rpA[d], j1 = G.rpA[d + 1];
        int j = j0;
        for (; j + 2 <= j1; j += 2) {
            int2 e0 = G.eA[j], e1 = G.eA[j + 1];
            float s0 = __int_as_float(e0.y), s1 = __int_as_float(e1.y);
            uint u0 = ((const uint*)(G.YA + (size_t)e0.x * 128))[lane];
            uint u1 = ((const uint*)(G.YA + (size_t)e1.x * 128))[lane];
            a0 = fmaf(__uint_as_float(u0 << 16), s0, a0);
            a1 = fmaf(__uint_as_float(u0 & 0xffff0000u), s0, a1);
            a0 = fmaf(__uint_as_float(u1 << 16), s1, a0);
            a1 = fmaf(__uint_as_float(u1 & 0xffff0000u), s1, a1);
        }
        if (j < j1) {
            int2 e0 = G.eA[j];
            float s0 = __int_as_float(e0.y);
            uint u0 = ((const uint*)(G.YA + (size_t)e0.x * 128))[lane];
            a0 = fmaf(__uint_as_float(u0 << 16), s0, a0);
            a1 = fmaf(__uint_as_float(u0 & 0xffff0000u), s0, a1);
        }
    }
    {
        int j0 = G.rpB[d], j1 = G.rpB[d + 1];
        int j = j0;
        for (; j + 2 <= j1; j += 2) {
            int2 e0 = G.eB[j], e1 = G.eB[j + 1];
            float s0 = __int_as_float(e0.y), s1 = __int_as_float(e1.y);
            uint u0 = ((const uint*)(G.YB + (size_t)e0.x * 128))[lane];
            uint u1 = ((const uint*)(G.YB + (size_t)e1.x * 128))[lane];
            b0 = fmaf(__uint_as_float(u0 << 16), s0, b0);
            b1 = fmaf(__uint_as_float(u0 & 0xffff0000u), s0, b1);
            b0 = fmaf(__uint_as_float(u1 << 16), s1, b0);
            b1 = fmaf(__uint_as_float(u1 & 0xffff0000u), s1, b1);
        }
        if (j < j1) {
            int2 e0 = G.eB[j];
            float s0 = __int_as_float(e0.y);
            uint u0 = ((const uint*)(G.YB + (size_t)e0.x * 128))[lane];
            b0 = fmaf(__uint_as_float(u0 << 16), s0, b0);
            b1 = fmaf(__uint_as_float(u0 & 0xffff0000u), s0, b1);
        }
    }
    float rA = G.rsdA[d], rB = G.rsdB[d];
    int c = lane * 2;
    float v0 = fmaf(a0, rA, fmaf(b0, rB, G.bA[c] + G.bB[c]));
    float v1 = fmaf(a1, rA, fmaf(b1, rB, G.bA[c + 1] + G.bB[c + 1]));
    if (OUT_BF16) {
        uint* o = blockIdx.y ? ob1 : ob0;
        o[(size_t)d * 64 + lane] = pk_bf16(v0, v1);
    } else {
        float* o = blockIdx.y ? of1 : of0;
        *reinterpret_cast<float2*>(o + (size_t)d * 128 + c) = make_float2(v0, v1);
    }
}

// ---------------- GRU + layer-2 transform: h = gru(relu(hcpre)); Z[2y+o] = h @ W2[2y+o] ----------------
__global__ __launch_bounds__(512) void gruz_kernel(
    const ushort* __restrict__ hcpre,
    const ushort* __restrict__ pk_h, const ushort* __restrict__ pk_l,
    const float* __restrict__ bih, const float* __restrict__ bhh,
    ushort* __restrict__ Z) {
    __shared__ __align__(16) ushort Xh[64 * 128];
    __shared__ __align__(16) ushort Hh[64 * 128];
    const int y = blockIdx.y;
    const ushort* xs = hcpre + (size_t)y * NU * 128;
    const int tid = threadIdx.x;
    const int row0 = blockIdx.x * 64;

    // ---- stage relu(x): x already bf16 -> exact staging (relu via sign test) ----
    {
        const int r = tid >> 3, q = tid & 7;
        const int gr = row0 + r;
        const ui32x4* xp = (const ui32x4*)(xs + (size_t)gr * 128 + q * 16);
#pragma unroll
        for (int k = 0; k < 2; ++k) {
            ui32x4 v = (gr < NN) ? xp[k] : (ui32x4)(0u);
#pragma unroll
            for (int t = 0; t < 4; ++t) {
                uint u = v[t];
                uint lo = (u & 0x8000u) ? 0u : (u & 0xFFFFu);
                uint hi = (u & 0x80000000u) ? 0u : (u & 0xFFFF0000u);
                v[t] = lo | hi;
            }
            int base = (r * 128 + q * 16 + k * 8) ^ ((r & 7) << 3);
            *reinterpret_cast<ui32x4*>(&Xh[base]) = v;
        }
    }
    __syncthreads();

    const int wv = tid >> 6, l = tid & 63;
    const int l15 = l & 15, lh = l >> 4;
    const int rh = wv >> 2, np = wv & 3;
    const ushort* gwh = pk_h + (size_t)8 * 16384;
    const ushort* gwl = pk_l + (size_t)8 * 16384;

    // ---- GRU gates GEMM: gi = x @ wih^T (split-W) ----
    f32x4 g3[3][2][2];
#pragma unroll
    for (int g = 0; g < 3; g++)
#pragma unroll
        for (int m = 0; m < 2; m++)
#pragma unroll
            for (int nfi = 0; nfi < 2; nfi++) g3[g][m][nfi] = (f32x4)(0.f);

#pragma unroll
    for (int ks = 0; ks < 4; ++ks) {
        bf16x8 aH[2];
#pragma unroll
        for (int m = 0; m < 2; ++m) {
            int row = rh * 32 + m * 16 + l15;
            int idx = (row * 128 + ks * 32 + lh * 8) ^ ((row & 7) << 3);
            aH[m] = *reinterpret_cast<const bf16x8*>(&Xh[idx]);
        }
#pragma unroll
        for (int g = 0; g < 3; ++g) {
#pragma unroll
            for (int nfi = 0; nfi < 2; ++nfi) {
                int gnf = g * 8 + np * 2 + nfi;
                size_t off = ((size_t)(gnf * 4 + ks) * 64 + l) * 8;
                bf16x8 bH = *reinterpret_cast<const bf16x8*>(gwh + off);
                bf16x8 bL = *reinterpret_cast<const bf16x8*>(gwl + off);
#pragma unroll
                for (int m = 0; m < 2; ++m) {
                    g3[g][m][nfi] = MFMA(aH[m], bH, g3[g][m][nfi]);
                    g3[g][m][nfi] = MFMA(aH[m], bL, g3[g][m][nfi]);
                }
            }
        }
    }

    // ---- gates (gh = bhh, h0 = 0); stage h bf16 into Hh (cvt_pk, biases hoisted) ----
#pragma unroll
    for (int nfi = 0; nfi < 2; ++nfi) {
        int c = (np * 2 + nfi) * 16 + l15;
        float b0 = bih[c] + bhh[c];
        float b1 = bih[128 + c] + bhh[128 + c];
        float b2i = bih[256 + c], b2h = bhh[256 + c];
#pragma unroll
        for (int m = 0; m < 2; ++m) {
#pragma unroll
            for (int i = 0; i < 4; ++i) {
                int rr = rh * 32 + m * 16 + lh * 4 + i;
                float rg = fsig(g3[0][m][nfi][i] + b0);
                float zz = fsig(g3[1][m][nfi][i] + b1);
                float nn = ftanh(g3[2][m][nfi][i] + b2i + rg * b2h);
                Hh[(rr * 128 + c) ^ ((rr & 7) << 3)] = f2bf1((1.f - zz) * nn);
            }
        }
    }
    __syncthreads();

    // ---- Z GEMMs: Z[2y+o] = h @ W2[2y+o] (split-W) ----
    f32x4 za[2][2][2];
#pragma unroll
    for (int o = 0; o < 2; o++)
#pragma unroll
        for (int m = 0; m < 2; m++)
#pragma unroll
            for (int nfi = 0; nfi < 2; nfi++) za[o][m][nfi] = (f32x4)(0.f);

#pragma unroll
    for (int ks = 0; ks < 4; ++ks) {
        bf16x8 aH[2];
#pragma unroll
        for (int m = 0; m < 2; ++m) {
            int row = rh * 32 + m * 16 + l15;
            int idx = (row * 128 + ks * 32 + lh * 8) ^ ((row & 7) << 3);
            aH[m] = *reinterpret_cast<const bf16x8*>(&Hh[idx]);
        }
#pragma unroll
        for (int o = 0; o < 2; ++o) {
            const ushort* wh = pk_h + (size_t)(4 + 2 * y + o) * 16384;
            const ushort* wl = pk_l + (size_t)(4 + 2 * y + o) * 16384;
#pragma unroll
            for (int nfi = 0; nfi < 2; ++nfi) {
                int nf = np * 2 + nfi;
                size_t off = ((size_t)(nf * 4 + ks) * 64 + l) * 8;
                bf16x8 bH = *reinterpret_cast<const bf16x8*>(wh + off);
                bf16x8 bL = *reinterpret_cast<const bf16x8*>(wl + off);
#pragma unroll
                for (int m = 0; m < 2; ++m) {
                    za[o][m][nfi] = MFMA(aH[m], bH, za[o][m][nfi]);
                    za[o][m][nfi] = MFMA(aH[m], bL, za[o][m][nfi]);
                }
            }
        }
    }

#pragma unroll
    for (int o = 0; o < 2; ++o) {
        ushort* Zo = Z + (size_t)(2 * y + o) * ((size_t)NN * 128);
#pragma unroll
        for (int m = 0; m < 2; ++m)
#pragma unroll
            for (int nfi = 0; nfi < 2; ++nfi) {
                int c = (np * 2 + nfi) * 16 + l15;
#pragma unroll
                for (int i = 0; i < 4; ++i) {
                    int gr = row0 + rh * 32 + m * 16 + lh * 4 + i;
                    if (gr < NN) Zo[(size_t)gr * 128 + c] = f2bf1(za[o][m][nfi][i]);
                }
            }
    }
}

// ---------------- launch ----------------
extern "C" void kernel_launch(void* const* d_in, const int* in_sizes, int n_in,
                              void* d_out, int out_size, void* d_ws, size_t ws_size,
                              hipStream_t stream) {
    const float* feat_user = (const float*)d_in[0];
    const float* feat_item = (const float*)d_in[1];

    // relation order: 0=follows(U->U) 1=buys(U->I) 2=revbuys(I->U) 3=similar(I->I)
    Ptr4 srcs = {{(const int*)d_in[3], (const int*)d_in[9], (const int*)d_in[15], (const int*)d_in[21]}};
    Ptr4 dsts = {{(const int*)d_in[4], (const int*)d_in[10], (const int*)d_in[16], (const int*)d_in[22]}};
    const float* b1[4] = {(const float*)d_in[6],  (const float*)d_in[12], (const float*)d_in[18], (const float*)d_in[24]};
    const float* b2[4] = {(const float*)d_in[8],  (const float*)d_in[14], (const float*)d_in[20], (const float*)d_in[26]};

    PackW pw = {{(const float*)d_in[5], (const float*)d_in[11], (const float*)d_in[17], (const float*)d_in[23],
                 (const float*)d_in[7], (const float*)d_in[13], (const float*)d_in[19], (const float*)d_in[25],
                 (const float*)d_in[27]}};
    const float* bih = (const float*)d_in[29];
    const float* bhh = (const float*)d_in[30];

    // ---- workspace ----
    char* w = (char*)d_ws;
    auto alloc = [&](size_t bytes) { char* r = w; w += (bytes + 255) & ~(size_t)255; return r; };
    int* cnt8         = (int*)alloc(8 * NN * sizeof(int));
    float* rs_src_all = (float*)alloc(4 * NN * sizeof(float));
    float* rs_dst_all = (float*)alloc(4 * NN * sizeof(float));
    int* row_ptr_all  = (int*)alloc(4 * (NN + 1) * sizeof(int));
    int2* edge_all    = (int2*)alloc((size_t)4 * NE * sizeof(int2));
    int* part         = (int*)alloc(4 * 128 * sizeof(int));
    ushort* pkh_all   = (ushort*)alloc((size_t)(8 * 16384 + 49152) * sizeof(ushort));
    ushort* pkl_all   = (ushort*)alloc((size_t)(8 * 16384 + 49152) * sizeof(ushort));
    ushort* Ybuf      = (ushort*)alloc((size_t)4 * NN * 128 * sizeof(ushort));  // Y then Z (reused)

    float* outLo = (float*)d_out;
    float* outHi = outLo + (size_t)NU * 128;
    ushort* hcpre = (ushort*)d_out;          // bf16 scratch in d_out (overwritten by final gathers)

    const int EB = (NE + 255) / 256;

    // ---- CSR build ----
    hipMemsetAsync(cnt8, 0, 8 * NN * sizeof(int), stream);
    hist8_kernel<<<dim3(EB, 8), 256, 0, stream>>>(srcs, dsts, cnt8);
    scan_phase_a<<<dim3(NB_SCAN, 4), 256, 0, stream>>>(cnt8, part);
    scan_phase_b<<<4, 128, 0, stream>>>(part);
    scan_phase_c<<<dim3(NB_SCAN, 4), 256, 0, stream>>>(cnt8, part, row_ptr_all, rs_dst_all);
    rsqrt_int_kernel<<<(4 * NN + 255) / 256, 256, 0, stream>>>(cnt8 + 4 * NN, rs_src_all, 4 * NN);
    fill4_kernel<<<dim3(EB, 4), 256, 0, stream>>>(srcs, dsts, rs_src_all, cnt8, edge_all);

    // ---- pack weights ----
    pack_all_kernel<<<(8 * 16384 + 49152 + 255) / 256, 256, 0, stream>>>(pw, pkh_all, pkl_all);

    const int GB = (NN + 63) / 64;   // 1563
    const int GGB = NN / 4;          // 25000 (4 rows/block)

    auto RP = [&](int r) { return row_ptr_all + r * (NN + 1); };
    auto EG = [&](int r) { return edge_all + (size_t)r * NE; };
    auto RD = [&](int r) { return rs_dst_all + r * NN; };
    auto YS = [&](int s) { return (const ushort*)(Ybuf + (size_t)s * NN * 128); };

    // ---- layer-1 transform: Y[0]=fu@W1f Y[1]=fu@W1b Y[2]=fi@W1r Y[3]=fi@W1s ----
    transform_kernel<<<dim3(GB, 2), 512, 0, stream>>>(feat_user, feat_item, pkh_all, pkl_all, Ybuf);

    // ---- layer-1 gathers (merged) -> hc_pre (bf16, in d_out scratch) ----
    {
        GPair gy0 = {YS(0), YS(2), RP(0), EG(0), RD(0), RP(2), EG(2), RD(2), b1[0], b1[2]};
        GPair gy1 = {YS(1), YS(3), RP(1), EG(1), RD(1), RP(3), EG(3), RD(3), b1[1], b1[3]};
        gather2_kernel<true><<<dim3(GGB, 2), 256, 0, stream>>>(
            gy0, gy1, (uint*)hcpre, (uint*)(hcpre + (size_t)NU * 128), nullptr, nullptr);
    }

    // ---- GRU + layer-2 transform: Z[0]=hu@W2f Z[1]=hu@W2b Z[2]=hi@W2r Z[3]=hi@W2s ----
    gruz_kernel<<<dim3(GB, 2), 512, 0, stream>>>(hcpre, pkh_all, pkl_all, bih, bhh, Ybuf);

    // ---- layer-2 gathers (merged) -> d_out (fp32) ----
    {
        GPair gy0 = {YS(0), YS(2), RP(0), EG(0), RD(0), RP(2), EG(2), RD(2), b2[0], b2[2]};
        GPair gy1 = {YS(1), YS(3), RP(1), EG(1), RD(1), RP(3), EG(3), RD(3), b2[1], b2[3]};
        gather2_kernel<false><<<dim3(GGB, 2), 256, 0, stream>>>(
            gy0, gy1, nullptr, nullptr, outLo, outHi);
    }
}

// Round 12
// 439.524 us; speedup vs baseline: 1.1757x; 1.1002x over previous
//
#include <hip/hip_runtime.h>
#include <math.h>

#define NU 100000
#define NI 100000
#define NE 200000
#define NTOT (NU + NI)
#define NN 100000
#define NB_SCAN ((NN + 1023) / 1024)   // 98

typedef __bf16 bf16x8 __attribute__((ext_vector_type(8)));
typedef float f32x4 __attribute__((ext_vector_type(4)));
typedef uint ui32x4 __attribute__((ext_vector_type(4)));
#define MFMA(a, b, c) __builtin_amdgcn_mfma_f32_16x16x32_bf16(a, b, c, 0, 0, 0)

__device__ __forceinline__ ushort f2bf(float f) {
    uint u = __float_as_uint(f);
    return (ushort)((u + 0x7FFFu + ((u >> 16) & 1u)) >> 16);
}
__device__ __forceinline__ float bf2f(ushort h) {
    return __uint_as_float(((uint)h) << 16);
}
// packed bf16 convert (single VALU op): lo16 = bf16(a), hi16 = bf16(b), RNE
__device__ __forceinline__ uint pk_bf16(float a, float b) {
    uint r;
    asm("v_cvt_pk_bf16_f32 %0, %1, %2" : "=v"(r) : "v"(a), "v"(b));
    return r;
}
// single-value bf16 via cvt_pk (1 op vs ~5 for software round)
__device__ __forceinline__ ushort f2bf1(float a) { return (ushort)(pk_bf16(a, a) & 0xffffu); }
__device__ __forceinline__ float fsig(float x) { return 1.f / (1.f + __expf(-x)); }
__device__ __forceinline__ float ftanh(float x) { return 1.f - 2.f / (1.f + __expf(2.f * x)); }

struct Ptr4 { const int* p[4]; };
struct PackW { const float* w[9]; };
struct GPair {
    const ushort* YA; const ushort* YB;
    const int* rpA; const int2* eA; const float* rsdA;
    const int* rpB; const int2* eB; const float* rsdB;
    const float* bA; const float* bB;
};

// ---------------- histogram: rels 0-3 = dst counts, 4-7 = src counts ----------------
__global__ void hist8_kernel(Ptr4 src, Ptr4 dst, int* __restrict__ cnt) {
    int e = blockIdx.x * blockDim.x + threadIdx.x;
    int r = blockIdx.y;
    if (e < NE) {
        const int* idx = (r < 4) ? dst.p[r] : src.p[r - 4];
        atomicAdd(&cnt[r * NN + idx[e]], 1);
    }
}

// ---------------- exclusive scan (3-phase) over NN ints x 4 rels ----------------
__global__ __launch_bounds__(256) void scan_phase_a(const int* __restrict__ in, int* __restrict__ part) {
    __shared__ int sh[256];
    int rel = blockIdx.y;
    const int* inp = in + rel * NN;
    int tid = threadIdx.x;
    int base = blockIdx.x * 1024 + tid * 4;
    int s = 0;
#pragma unroll
    for (int i = 0; i < 4; i++) { int idx = base + i; if (idx < NN) s += inp[idx]; }
    sh[tid] = s; __syncthreads();
    for (int off = 128; off > 0; off >>= 1) {
        if (tid < off) sh[tid] += sh[tid + off];
        __syncthreads();
    }
    if (tid == 0) part[rel * 128 + blockIdx.x] = sh[0];
}

__global__ void scan_phase_b(int* __restrict__ part) {
    __shared__ int sh[128];
    int rel = blockIdx.x;
    int tid = threadIdx.x;
    int v = (tid < NB_SCAN) ? part[rel * 128 + tid] : 0;
    sh[tid] = v; __syncthreads();
    for (int off = 1; off < 128; off <<= 1) {
        int t = (tid >= off) ? sh[tid - off] : 0;
        __syncthreads();
        sh[tid] += t;
        __syncthreads();
    }
    if (tid < NB_SCAN) part[rel * 128 + tid] = sh[tid] - v;   // exclusive
}

__global__ __launch_bounds__(256) void scan_phase_c(int* __restrict__ cnt, const int* __restrict__ part,
                                                    int* __restrict__ row_ptr, float* __restrict__ rs) {
    __shared__ int sh[256];
    int rel = blockIdx.y;
    int* inp = cnt + rel * NN;
    int* rp = row_ptr + rel * (NN + 1);
    float* rsd = rs + rel * NN;
    int tid = threadIdx.x;
    int base = blockIdx.x * 1024 + tid * 4;
    int v[4]; int s = 0;
#pragma unroll
    for (int i = 0; i < 4; i++) { int idx = base + i; v[i] = (idx < NN) ? inp[idx] : 0; s += v[i]; }
    sh[tid] = s; __syncthreads();
    for (int off = 1; off < 256; off <<= 1) {
        int t = (tid >= off) ? sh[tid - off] : 0;
        __syncthreads();
        sh[tid] += t;
        __syncthreads();
    }
    int excl = sh[tid] - s + part[rel * 128 + blockIdx.x];
#pragma unroll
    for (int i = 0; i < 4; i++) {
        int idx = base + i;
        if (idx < NN) {
            rp[idx] = excl;
            inp[idx] = excl;                     // cursor init
            rsd[idx] = rsqrtf(fmaxf((float)v[i], 1.0f));
            excl += v[i];
        }
    }
    if (blockIdx.x == 0 && tid == 0) rp[NN] = NE;
}

// cursor in cnt[0..4NN); src counts in cnt_src = cnt + 4NN (rs_src computed inline)
__global__ void fill4_kernel(Ptr4 src, Ptr4 dst, int* __restrict__ cursor,
                             const int* __restrict__ cnt_src, int2* __restrict__ edge) {
    int e = blockIdx.x * blockDim.x + threadIdx.x;
    int r = blockIdx.y;
    if (e >= NE) return;
    int s = src.p[r][e], d = dst.p[r][e];
    int p = atomicAdd(&cursor[r * NN + d], 1);
    float rs = rsqrtf(fmaxf((float)cnt_src[r * NN + s], 1.0f));
    edge[(size_t)r * NE + p] = make_int2(s, __float_as_int(rs));
}

// ---------------- weight pack (single bf16, MFMA B-fragment order) ----------------
// pack[((nf*4 + ks)*64 + l)*8 + j] = B[ks*32 + (l>>4)*8 + j][nf*16 + (l&15)]
__global__ void pack_all_kernel(PackW pw, ushort* __restrict__ hi) {
    int tid = blockIdx.x * blockDim.x + threadIdx.x;
    int wi, local, N, trans;
    if (tid < 8 * 16384) { wi = tid >> 14; local = tid & 16383; N = 128; trans = 0; }
    else {
        int t = tid - 8 * 16384;
        if (t >= 49152) return;
        wi = 8; local = t; N = 384; trans = 1;
    }
    int j = local & 7;
    int l = (local >> 3) & 63;
    int ks = (local >> 9) & 3;
    int nf = local >> 11;
    int k = ks * 32 + ((l >> 4) << 3) + j;
    int n = nf * 16 + (l & 15);
    const float* W = pw.w[wi];
    float v = trans ? W[(size_t)n * 128 + k] : W[(size_t)k * N + n];
    hi[(size_t)wi * 16384 + local] = f2bf(v);
}

// ---------------- transform: Y[2y+o] = feats(y) @ W1[2y+o], bf16 out ----------------
// split-A x single-W (2 MFMA): A near-exact, one W rounding, one bf16 store rounding.
__global__ __launch_bounds__(512) void transform_kernel(
    const float* __restrict__ xu, const float* __restrict__ xi,
    const ushort* __restrict__ pk_h, ushort* __restrict__ Y) {
    __shared__ __align__(16) ushort Ah[64 * 128];
    __shared__ __align__(16) ushort Al[64 * 128];
    const int y = blockIdx.y;
    const float* x = y ? xi : xu;
    const int tid = threadIdx.x;
    const int row0 = blockIdx.x * 64;

    // ---- stage: fp32 -> split bf16 via cvt_pk pairs ----
    {
        const int r = tid >> 3, q = tid & 7;
        const int gr = row0 + r;
        const f32x4* xp = (const f32x4*)(x + (size_t)gr * 128 + q * 16);
#pragma unroll
        for (int k = 0; k < 4; ++k) {
            f32x4 v = (gr < NN) ? xp[k] : (f32x4)(0.f);
            uint h01 = pk_bf16(v[0], v[1]);
            uint h23 = pk_bf16(v[2], v[3]);
            float r0 = v[0] - __uint_as_float(h01 << 16);
            float r1 = v[1] - __uint_as_float(h01 & 0xffff0000u);
            float r2 = v[2] - __uint_as_float(h23 << 16);
            float r3 = v[3] - __uint_as_float(h23 & 0xffff0000u);
            uint l01 = pk_bf16(r0, r1);
            uint l23 = pk_bf16(r2, r3);
            int base = (r * 128 + q * 16 + k * 4) ^ ((r & 7) << 3);
            *reinterpret_cast<uint2*>(&Ah[base]) = make_uint2(h01, h23);
            *reinterpret_cast<uint2*>(&Al[base]) = make_uint2(l01, l23);
        }
    }
    __syncthreads();

    const int wv = tid >> 6, l = tid & 63;
    const int l15 = l & 15, lh = l >> 4;
    const int rh = wv >> 2, np = wv & 3;

    f32x4 acc[2][2][2];   // [o][m][nfi]
#pragma unroll
    for (int o = 0; o < 2; o++)
#pragma unroll
        for (int m = 0; m < 2; m++)
#pragma unroll
            for (int nfi = 0; nfi < 2; nfi++) acc[o][m][nfi] = (f32x4)(0.f);

#pragma unroll
    for (int ks = 0; ks < 4; ++ks) {
        bf16x8 aH[2], aL[2];
#pragma unroll
        for (int m = 0; m < 2; ++m) {
            int row = rh * 32 + m * 16 + l15;
            int idx = (row * 128 + ks * 32 + lh * 8) ^ ((row & 7) << 3);
            aH[m] = *reinterpret_cast<const bf16x8*>(&Ah[idx]);
            aL[m] = *reinterpret_cast<const bf16x8*>(&Al[idx]);
        }
#pragma unroll
        for (int o = 0; o < 2; ++o) {
            const ushort* wh = pk_h + (size_t)(2 * y + o) * 16384;
#pragma unroll
            for (int nfi = 0; nfi < 2; ++nfi) {
                int nf = np * 2 + nfi;
                size_t off = ((size_t)(nf * 4 + ks) * 64 + l) * 8;
                bf16x8 bH = *reinterpret_cast<const bf16x8*>(wh + off);
#pragma unroll
                for (int m = 0; m < 2; ++m) {
                    acc[o][m][nfi] = MFMA(aH[m], bH, acc[o][m][nfi]);
                    acc[o][m][nfi] = MFMA(aL[m], bH, acc[o][m][nfi]);
                }
            }
        }
    }

#pragma unroll
    for (int o = 0; o < 2; ++o) {
        ushort* Yo = Y + (size_t)(2 * y + o) * ((size_t)NN * 128);
#pragma unroll
        for (int m = 0; m < 2; ++m)
#pragma unroll
            for (int nfi = 0; nfi < 2; ++nfi) {
                int c = (np * 2 + nfi) * 16 + l15;
#pragma unroll
                for (int i = 0; i < 4; ++i) {
                    int gr = row0 + rh * 32 + m * 16 + lh * 4 + i;
                    if (gr < NN) Yo[(size_t)gr * 128 + c] = f2bf1(acc[o][m][nfi][i]);
                }
            }
    }
}

// ---------------- merged dual gather: out[d] = rsdA*sum(scl*YA[s]) + rsdB*sum(scl*YB[s]) + bA + bB ----------------
// one wave per dst row; lane owns cols 2l, 2l+1 (one uint of the bf16 row per edge).
template <bool OUT_BF16>
__global__ __launch_bounds__(256) void gather2_kernel(GPair g0, GPair g1,
                                                      uint* __restrict__ ob0, uint* __restrict__ ob1,
                                                      float* __restrict__ of0, float* __restrict__ of1) {
    const GPair G = blockIdx.y ? g1 : g0;
    const int d = blockIdx.x * 4 + (threadIdx.x >> 6);
    const int lane = threadIdx.x & 63;

    float a0 = 0.f, a1 = 0.f, b0 = 0.f, b1 = 0.f;
    {
        int j0 = G.rpA[d], j1 = G.rpA[d + 1];
        int j = j0;
        for (; j + 2 <= j1; j += 2) {
            int2 e0 = G.eA[j], e1 = G.eA[j + 1];
            float s0 = __int_as_float(e0.y), s1 = __int_as_float(e1.y);
            uint u0 = ((const uint*)(G.YA + (size_t)e0.x * 128))[lane];
            uint u1 = ((const uint*)(G.YA + (size_t)e1.x * 128))[lane];
            a0 = fmaf(__uint_as_float(u0 << 16), s0, a0);
            a1 = fmaf(__uint_as_float(u0 & 0xffff0000u), s0, a1);
            a0 = fmaf(__uint_as_float(u1 << 16), s1, a0);
            a1 = fmaf(__uint_as_float(u1 & 0xffff0000u), s1, a1);
        }
        if (j < j1) {
            int2 e0 = G.eA[j];
            float s0 = __int_as_float(e0.y);
            uint u0 = ((const uint*)(G.YA + (size_t)e0.x * 128))[lane];
            a0 = fmaf(__uint_as_float(u0 << 16), s0, a0);
            a1 = fmaf(__uint_as_float(u0 & 0xffff0000u), s0, a1);
        }
    }
    {
        int j0 = G.rpB[d], j1 = G.rpB[d + 1];
        int j = j0;
        for (; j + 2 <= j1; j += 2) {
            int2 e0 = G.eB[j], e1 = G.eB[j + 1];
            float s0 = __int_as_float(e0.y), s1 = __int_as_float(e1.y);
            uint u0 = ((const uint*)(G.YB + (size_t)e0.x * 128))[lane];
            uint u1 = ((const uint*)(G.YB + (size_t)e1.x * 128))[lane];
            b0 = fmaf(__uint_as_float(u0 << 16), s0, b0);
            b1 = fmaf(__uint_as_float(u0 & 0xffff0000u), s0, b1);
            b0 = fmaf(__uint_as_float(u1 << 16), s1, b0);
            b1 = fmaf(__uint_as_float(u1 & 0xffff0000u), s1, b1);
        }
        if (j < j1) {
            int2 e0 = G.eB[j];
            float s0 = __int_as_float(e0.y);
            uint u0 = ((const uint*)(G.YB + (size_t)e0.x * 128))[lane];
            b0 = fmaf(__uint_as_float(u0 << 16), s0, b0);
            b1 = fmaf(__uint_as_float(u0 & 0xffff0000u), s0, b1);
        }
    }
    float rA = G.rsdA[d], rB = G.rsdB[d];
    int c = lane * 2;
    float v0 = fmaf(a0, rA, fmaf(b0, rB, G.bA[c] + G.bB[c]));
    float v1 = fmaf(a1, rA, fmaf(b1, rB, G.bA[c + 1] + G.bB[c + 1]));
    if (OUT_BF16) {
        uint* o = blockIdx.y ? ob1 : ob0;
        o[(size_t)d * 64 + lane] = pk_bf16(v0, v1);
    } else {
        float* o = blockIdx.y ? of1 : of0;
        *reinterpret_cast<float2*>(o + (size_t)d * 128 + c) = make_float2(v0, v1);
    }
}

// ---------------- GRU + layer-2 transform: h = gru(relu(hcpre)); Z[2y+o] = h @ W2[2y+o] ----------------
__global__ __launch_bounds__(512) void gruz_kernel(
    const ushort* __restrict__ hcpre,
    const ushort* __restrict__ pk_h,
    const float* __restrict__ bih, const float* __restrict__ bhh,
    ushort* __restrict__ Z) {
    __shared__ __align__(16) ushort Xh[64 * 128];
    __shared__ __align__(16) ushort Hh[64 * 128];
    const int y = blockIdx.y;
    const ushort* xs = hcpre + (size_t)y * NU * 128;
    const int tid = threadIdx.x;
    const int row0 = blockIdx.x * 64;

    // ---- stage relu(x): x already bf16 -> exact staging (relu via sign test) ----
    {
        const int r = tid >> 3, q = tid & 7;
        const int gr = row0 + r;
        const ui32x4* xp = (const ui32x4*)(xs + (size_t)gr * 128 + q * 16);
#pragma unroll
        for (int k = 0; k < 2; ++k) {
            ui32x4 v = (gr < NN) ? xp[k] : (ui32x4)(0u);
#pragma unroll
            for (int t = 0; t < 4; ++t) {
                uint u = v[t];
                uint lo = (u & 0x8000u) ? 0u : (u & 0xFFFFu);
                uint hi = (u & 0x80000000u) ? 0u : (u & 0xFFFF0000u);
                v[t] = lo | hi;
            }
            int base = (r * 128 + q * 16 + k * 8) ^ ((r & 7) << 3);
            *reinterpret_cast<ui32x4*>(&Xh[base]) = v;
        }
    }
    __syncthreads();

    const int wv = tid >> 6, l = tid & 63;
    const int l15 = l & 15, lh = l >> 4;
    const int rh = wv >> 2, np = wv & 3;
    const ushort* gwh = pk_h + (size_t)8 * 16384;

    // ---- GRU gates GEMM: gi = x @ wih^T ----
    f32x4 g3[3][2][2];
#pragma unroll
    for (int g = 0; g < 3; g++)
#pragma unroll
        for (int m = 0; m < 2; m++)
#pragma unroll
            for (int nfi = 0; nfi < 2; nfi++) g3[g][m][nfi] = (f32x4)(0.f);

#pragma unroll
    for (int ks = 0; ks < 4; ++ks) {
        bf16x8 aH[2];
#pragma unroll
        for (int m = 0; m < 2; ++m) {
            int row = rh * 32 + m * 16 + l15;
            int idx = (row * 128 + ks * 32 + lh * 8) ^ ((row & 7) << 3);
            aH[m] = *reinterpret_cast<const bf16x8*>(&Xh[idx]);
        }
#pragma unroll
        for (int g = 0; g < 3; ++g) {
#pragma unroll
            for (int nfi = 0; nfi < 2; ++nfi) {
                int gnf = g * 8 + np * 2 + nfi;
                size_t off = ((size_t)(gnf * 4 + ks) * 64 + l) * 8;
                bf16x8 bH = *reinterpret_cast<const bf16x8*>(gwh + off);
#pragma unroll
                for (int m = 0; m < 2; ++m)
                    g3[g][m][nfi] = MFMA(aH[m], bH, g3[g][m][nfi]);
            }
        }
    }

    // ---- gates (gh = bhh, h0 = 0); stage h bf16 into Hh (cvt_pk, biases hoisted) ----
#pragma unroll
    for (int nfi = 0; nfi < 2; ++nfi) {
        int c = (np * 2 + nfi) * 16 + l15;
        float b0 = bih[c] + bhh[c];
        float b1 = bih[128 + c] + bhh[128 + c];
        float b2i = bih[256 + c], b2h = bhh[256 + c];
#pragma unroll
        for (int m = 0; m < 2; ++m) {
#pragma unroll
            for (int i = 0; i < 4; ++i) {
                int rr = rh * 32 + m * 16 + lh * 4 + i;
                float rg = fsig(g3[0][m][nfi][i] + b0);
                float zz = fsig(g3[1][m][nfi][i] + b1);
                float nn = ftanh(g3[2][m][nfi][i] + b2i + rg * b2h);
                Hh[(rr * 128 + c) ^ ((rr & 7) << 3)] = f2bf1((1.f - zz) * nn);
            }
        }
    }
    __syncthreads();

    // ---- Z GEMMs: Z[2y+o] = h @ W2[2y+o] ----
    f32x4 za[2][2][2];
#pragma unroll
    for (int o = 0; o < 2; o++)
#pragma unroll
        for (int m = 0; m < 2; m++)
#pragma unroll
            for (int nfi = 0; nfi < 2; nfi++) za[o][m][nfi] = (f32x4)(0.f);

#pragma unroll
    for (int ks = 0; ks < 4; ++ks) {
        bf16x8 aH[2];
#pragma unroll
        for (int m = 0; m < 2; ++m) {
            int row = rh * 32 + m * 16 + l15;
            int idx = (row * 128 + ks * 32 + lh * 8) ^ ((row & 7) << 3);
            aH[m] = *reinterpret_cast<const bf16x8*>(&Hh[idx]);
        }
#pragma unroll
        for (int o = 0; o < 2; ++o) {
            const ushort* wh = pk_h + (size_t)(4 + 2 * y + o) * 16384;
#pragma unroll
            for (int nfi = 0; nfi < 2; ++nfi) {
                int nf = np * 2 + nfi;
                size_t off = ((size_t)(nf * 4 + ks) * 64 + l) * 8;
                bf16x8 bH = *reinterpret_cast<const bf16x8*>(wh + off);
#pragma unroll
                for (int m = 0; m < 2; ++m)
                    za[o][m][nfi] = MFMA(aH[m], bH, za[o][m][nfi]);
            }
        }
    }

#pragma unroll
    for (int o = 0; o < 2; ++o) {
        ushort* Zo = Z + (size_t)(2 * y + o) * ((size_t)NN * 128);
#pragma unroll
        for (int m = 0; m < 2; ++m)
#pragma unroll
            for (int nfi = 0; nfi < 2; ++nfi) {
                int c = (np * 2 + nfi) * 16 + l15;
#pragma unroll
                for (int i = 0; i < 4; ++i) {
                    int gr = row0 + rh * 32 + m * 16 + lh * 4 + i;
                    if (gr < NN) Zo[(size_t)gr * 128 + c] = f2bf1(za[o][m][nfi][i]);
                }
            }
    }
}

// ---------------- launch ----------------
extern "C" void kernel_launch(void* const* d_in, const int* in_sizes, int n_in,
                              void* d_out, int out_size, void* d_ws, size_t ws_size,
                              hipStream_t stream) {
    const float* feat_user = (const float*)d_in[0];
    const float* feat_item = (const float*)d_in[1];

    // relation order: 0=follows(U->U) 1=buys(U->I) 2=revbuys(I->U) 3=similar(I->I)
    Ptr4 srcs = {{(const int*)d_in[3], (const int*)d_in[9], (const int*)d_in[15], (const int*)d_in[21]}};
    Ptr4 dsts = {{(const int*)d_in[4], (const int*)d_in[10], (const int*)d_in[16], (const int*)d_in[22]}};
    const float* b1[4] = {(const float*)d_in[6],  (const float*)d_in[12], (const float*)d_in[18], (const float*)d_in[24]};
    const float* b2[4] = {(const float*)d_in[8],  (const float*)d_in[14], (const float*)d_in[20], (const float*)d_in[26]};

    PackW pw = {{(const float*)d_in[5], (const float*)d_in[11], (const float*)d_in[17], (const float*)d_in[23],
                 (const float*)d_in[7], (const float*)d_in[13], (const float*)d_in[19], (const float*)d_in[25],
                 (const float*)d_in[27]}};
    const float* bih = (const float*)d_in[29];
    const float* bhh = (const float*)d_in[30];

    // ---- workspace ----
    char* w = (char*)d_ws;
    auto alloc = [&](size_t bytes) { char* r = w; w += (bytes + 255) & ~(size_t)255; return r; };
    int* cnt8         = (int*)alloc(8 * NN * sizeof(int));
    float* rs_dst_all = (float*)alloc(4 * NN * sizeof(float));
    int* row_ptr_all  = (int*)alloc(4 * (NN + 1) * sizeof(int));
    int2* edge_all    = (int2*)alloc((size_t)4 * NE * sizeof(int2));
    int* part         = (int*)alloc(4 * 128 * sizeof(int));
    ushort* pkh_all   = (ushort*)alloc((size_t)(8 * 16384 + 49152) * sizeof(ushort));
    ushort* Ybuf      = (ushort*)alloc((size_t)4 * NN * 128 * sizeof(ushort));  // Y then Z (reused)

    float* outLo = (float*)d_out;
    float* outHi = outLo + (size_t)NU * 128;
    ushort* hcpre = (ushort*)d_out;          // bf16 scratch in d_out (overwritten by final gathers)

    const int EB = (NE + 255) / 256;

    // ---- CSR build ----
    hipMemsetAsync(cnt8, 0, 8 * NN * sizeof(int), stream);
    hist8_kernel<<<dim3(EB, 8), 256, 0, stream>>>(srcs, dsts, cnt8);
    scan_phase_a<<<dim3(NB_SCAN, 4), 256, 0, stream>>>(cnt8, part);
    scan_phase_b<<<4, 128, 0, stream>>>(part);
    scan_phase_c<<<dim3(NB_SCAN, 4), 256, 0, stream>>>(cnt8, part, row_ptr_all, rs_dst_all);
    fill4_kernel<<<dim3(EB, 4), 256, 0, stream>>>(srcs, dsts, cnt8, cnt8 + 4 * NN, edge_all);

    // ---- pack weights ----
    pack_all_kernel<<<(8 * 16384 + 49152 + 255) / 256, 256, 0, stream>>>(pw, pkh_all);

    const int GB = (NN + 63) / 64;   // 1563
    const int GGB = NN / 4;          // 25000 (4 rows/block)

    auto RP = [&](int r) { return row_ptr_all + r * (NN + 1); };
    auto EG = [&](int r) { return edge_all + (size_t)r * NE; };
    auto RD = [&](int r) { return rs_dst_all + r * NN; };
    auto YS = [&](int s) { return (const ushort*)(Ybuf + (size_t)s * NN * 128); };

    // ---- layer-1 transform: Y[0]=fu@W1f Y[1]=fu@W1b Y[2]=fi@W1r Y[3]=fi@W1s ----
    transform_kernel<<<dim3(GB, 2), 512, 0, stream>>>(feat_user, feat_item, pkh_all, Ybuf);

    // ---- layer-1 gathers (merged) -> hc_pre (bf16, in d_out scratch) ----
    {
        GPair gy0 = {YS(0), YS(2), RP(0), EG(0), RD(0), RP(2), EG(2), RD(2), b1[0], b1[2]};
        GPair gy1 = {YS(1), YS(3), RP(1), EG(1), RD(1), RP(3), EG(3), RD(3), b1[1], b1[3]};
        gather2_kernel<true><<<dim3(GGB, 2), 256, 0, stream>>>(
            gy0, gy1, (uint*)hcpre, (uint*)(hcpre + (size_t)NU * 128), nullptr, nullptr);
    }

    // ---- GRU + layer-2 transform: Z[0]=hu@W2f Z[1]=hu@W2b Z[2]=hi@W2r Z[3]=hi@W2s ----
    gruz_kernel<<<dim3(GB, 2), 512, 0, stream>>>(hcpre, pkh_all, bih, bhh, Ybuf);

    // ---- layer-2 gathers (merged) -> d_out (fp32) ----
    {
        GPair gy0 = {YS(0), YS(2), RP(0), EG(0), RD(0), RP(2), EG(2), RD(2), b2[0], b2[2]};
        GPair gy1 = {YS(1), YS(3), RP(1), EG(1), RD(1), RP(3), EG(3), RD(3), b2[1], b2[3]};
        gather2_kernel<false><<<dim3(GGB, 2), 256, 0, stream>>>(
            gy0, gy1, nullptr, nullptr, outLo, outHi);
    }
}

// Round 13
// 357.418 us; speedup vs baseline: 1.4458x; 1.2297x over previous
//
#include <hip/hip_runtime.h>
#include <math.h>

#define NU 100000
#define NI 100000
#define NE 200000
#define NTOT (NU + NI)
#define NN 100000
#define NB_SCAN ((NN + 1023) / 1024)   // 98

typedef __bf16 bf16x8 __attribute__((ext_vector_type(8)));
typedef float f32x4 __attribute__((ext_vector_type(4)));
typedef uint ui32x4 __attribute__((ext_vector_type(4)));
#define MFMA(a, b, c) __builtin_amdgcn_mfma_f32_16x16x32_bf16(a, b, c, 0, 0, 0)

__device__ __forceinline__ ushort f2bf(float f) {
    uint u = __float_as_uint(f);
    return (ushort)((u + 0x7FFFu + ((u >> 16) & 1u)) >> 16);
}
__device__ __forceinline__ float bf2f(ushort h) {
    return __uint_as_float(((uint)h) << 16);
}
// packed bf16 convert (single VALU op): lo16 = bf16(a), hi16 = bf16(b), RNE
__device__ __forceinline__ uint pk_bf16(float a, float b) {
    uint r;
    asm("v_cvt_pk_bf16_f32 %0, %1, %2" : "=v"(r) : "v"(a), "v"(b));
    return r;
}
// single-value bf16 via cvt_pk (1 op vs ~5 for software round)
__device__ __forceinline__ ushort f2bf1(float a) { return (ushort)(pk_bf16(a, a) & 0xffffu); }
__device__ __forceinline__ float fsig(float x) { return 1.f / (1.f + __expf(-x)); }
__device__ __forceinline__ float ftanh(float x) { return 1.f - 2.f / (1.f + __expf(2.f * x)); }

struct Ptr4 { const int* p[4]; };
struct PackW { const float* w[9]; };
struct GPair {
    const ushort* YA; const ushort* YB;
    const int* rpA; const int2* eA; const float* rsdA;
    const int* rpB; const int2* eB; const float* rsdB;
    const float* bA; const float* bB;
};

// ---------------- histogram: rels 0-3 = dst counts, 4-7 = src counts ----------------
__global__ void hist8_kernel(Ptr4 src, Ptr4 dst, int* __restrict__ cnt) {
    int e = blockIdx.x * blockDim.x + threadIdx.x;
    int r = blockIdx.y;
    if (e < NE) {
        const int* idx = (r < 4) ? dst.p[r] : src.p[r - 4];
        atomicAdd(&cnt[r * NN + idx[e]], 1);
    }
}

// ---------------- exclusive scan (3-phase) over NN ints x 4 rels ----------------
__global__ __launch_bounds__(256) void scan_phase_a(const int* __restrict__ in, int* __restrict__ part) {
    __shared__ int sh[256];
    int rel = blockIdx.y;
    const int* inp = in + rel * NN;
    int tid = threadIdx.x;
    int base = blockIdx.x * 1024 + tid * 4;
    int s = 0;
#pragma unroll
    for (int i = 0; i < 4; i++) { int idx = base + i; if (idx < NN) s += inp[idx]; }
    sh[tid] = s; __syncthreads();
    for (int off = 128; off > 0; off >>= 1) {
        if (tid < off) sh[tid] += sh[tid + off];
        __syncthreads();
    }
    if (tid == 0) part[rel * 128 + blockIdx.x] = sh[0];
}

__global__ void scan_phase_b(int* __restrict__ part) {
    __shared__ int sh[128];
    int rel = blockIdx.x;
    int tid = threadIdx.x;
    int v = (tid < NB_SCAN) ? part[rel * 128 + tid] : 0;
    sh[tid] = v; __syncthreads();
    for (int off = 1; off < 128; off <<= 1) {
        int t = (tid >= off) ? sh[tid - off] : 0;
        __syncthreads();
        sh[tid] += t;
        __syncthreads();
    }
    if (tid < NB_SCAN) part[rel * 128 + tid] = sh[tid] - v;   // exclusive
}

__global__ __launch_bounds__(256) void scan_phase_c(int* __restrict__ cnt, const int* __restrict__ part,
                                                    int* __restrict__ row_ptr, float* __restrict__ rs) {
    __shared__ int sh[256];
    int rel = blockIdx.y;
    int* inp = cnt + rel * NN;
    int* rp = row_ptr + rel * (NN + 1);
    float* rsd = rs + rel * NN;
    int tid = threadIdx.x;
    int base = blockIdx.x * 1024 + tid * 4;
    int v[4]; int s = 0;
#pragma unroll
    for (int i = 0; i < 4; i++) { int idx = base + i; v[i] = (idx < NN) ? inp[idx] : 0; s += v[i]; }
    sh[tid] = s; __syncthreads();
    for (int off = 1; off < 256; off <<= 1) {
        int t = (tid >= off) ? sh[tid - off] : 0;
        __syncthreads();
        sh[tid] += t;
        __syncthreads();
    }
    int excl = sh[tid] - s + part[rel * 128 + blockIdx.x];
#pragma unroll
    for (int i = 0; i < 4; i++) {
        int idx = base + i;
        if (idx < NN) {
            rp[idx] = excl;
            inp[idx] = excl;                     // cursor init
            rsd[idx] = rsqrtf(fmaxf((float)v[i], 1.0f));
            excl += v[i];
        }
    }
    if (blockIdx.x == 0 && tid == 0) rp[NN] = NE;
}

// cursor in cnt[0..4NN); src counts in cnt_src = cnt + 4NN (rs_src computed inline)
__global__ void fill4_kernel(Ptr4 src, Ptr4 dst, int* __restrict__ cursor,
                             const int* __restrict__ cnt_src, int2* __restrict__ edge) {
    int e = blockIdx.x * blockDim.x + threadIdx.x;
    int r = blockIdx.y;
    if (e >= NE) return;
    int s = src.p[r][e], d = dst.p[r][e];
    int p = atomicAdd(&cursor[r * NN + d], 1);
    float rs = rsqrtf(fmaxf((float)cnt_src[r * NN + s], 1.0f));
    edge[(size_t)r * NE + p] = make_int2(s, __float_as_int(rs));
}

// ---------------- weight pack (single bf16, MFMA B-fragment order) ----------------
// pack[((nf*4 + ks)*64 + l)*8 + j] = B[ks*32 + (l>>4)*8 + j][nf*16 + (l&15)]
__global__ void pack_all_kernel(PackW pw, ushort* __restrict__ hi) {
    int tid = blockIdx.x * blockDim.x + threadIdx.x;
    int wi, local, N, trans;
    if (tid < 8 * 16384) { wi = tid >> 14; local = tid & 16383; N = 128; trans = 0; }
    else {
        int t = tid - 8 * 16384;
        if (t >= 49152) return;
        wi = 8; local = t; N = 384; trans = 1;
    }
    int j = local & 7;
    int l = (local >> 3) & 63;
    int ks = (local >> 9) & 3;
    int nf = local >> 11;
    int k = ks * 32 + ((l >> 4) << 3) + j;
    int n = nf * 16 + (l & 15);
    const float* W = pw.w[wi];
    float v = trans ? W[(size_t)n * 128 + k] : W[(size_t)k * N + n];
    hi[(size_t)wi * 16384 + local] = f2bf(v);
}

// ---------------- transform: Y[2y+o] = feats(y) @ W1[2y+o], bf16 out ----------------
// split-A x single-W (2 MFMA): A near-exact, one W rounding, one bf16 store rounding.
__global__ __launch_bounds__(512) void transform_kernel(
    const float* __restrict__ xu, const float* __restrict__ xi,
    const ushort* __restrict__ pk_h, ushort* __restrict__ Y) {
    __shared__ __align__(16) ushort Ah[64 * 128];
    __shared__ __align__(16) ushort Al[64 * 128];
    const int y = blockIdx.y;
    const float* x = y ? xi : xu;
    const int tid = threadIdx.x;
    const int row0 = blockIdx.x * 64;

    // ---- stage: fp32 -> split bf16 via cvt_pk pairs ----
    {
        const int r = tid >> 3, q = tid & 7;
        const int gr = row0 + r;
        const f32x4* xp = (const f32x4*)(x + (size_t)gr * 128 + q * 16);
#pragma unroll
        for (int k = 0; k < 4; ++k) {
            f32x4 v = (gr < NN) ? xp[k] : (f32x4)(0.f);
            uint h01 = pk_bf16(v[0], v[1]);
            uint h23 = pk_bf16(v[2], v[3]);
            float r0 = v[0] - __uint_as_float(h01 << 16);
            float r1 = v[1] - __uint_as_float(h01 & 0xffff0000u);
            float r2 = v[2] - __uint_as_float(h23 << 16);
            float r3 = v[3] - __uint_as_float(h23 & 0xffff0000u);
            uint l01 = pk_bf16(r0, r1);
            uint l23 = pk_bf16(r2, r3);
            int base = (r * 128 + q * 16 + k * 4) ^ ((r & 7) << 3);
            *reinterpret_cast<uint2*>(&Ah[base]) = make_uint2(h01, h23);
            *reinterpret_cast<uint2*>(&Al[base]) = make_uint2(l01, l23);
        }
    }
    __syncthreads();

    const int wv = tid >> 6, l = tid & 63;
    const int l15 = l & 15, lh = l >> 4;
    const int rh = wv >> 2, np = wv & 3;

    f32x4 acc[2][2][2];   // [o][m][nfi]
#pragma unroll
    for (int o = 0; o < 2; o++)
#pragma unroll
        for (int m = 0; m < 2; m++)
#pragma unroll
            for (int nfi = 0; nfi < 2; nfi++) acc[o][m][nfi] = (f32x4)(0.f);

#pragma unroll
    for (int ks = 0; ks < 4; ++ks) {
        bf16x8 aH[2], aL[2];
#pragma unroll
        for (int m = 0; m < 2; ++m) {
            int row = rh * 32 + m * 16 + l15;
            int idx = (row * 128 + ks * 32 + lh * 8) ^ ((row & 7) << 3);
            aH[m] = *reinterpret_cast<const bf16x8*>(&Ah[idx]);
            aL[m] = *reinterpret_cast<const bf16x8*>(&Al[idx]);
        }
#pragma unroll
        for (int o = 0; o < 2; ++o) {
            const ushort* wh = pk_h + (size_t)(2 * y + o) * 16384;
#pragma unroll
            for (int nfi = 0; nfi < 2; ++nfi) {
                int nf = np * 2 + nfi;
                size_t off = ((size_t)(nf * 4 + ks) * 64 + l) * 8;
                bf16x8 bH = *reinterpret_cast<const bf16x8*>(wh + off);
#pragma unroll
                for (int m = 0; m < 2; ++m) {
                    acc[o][m][nfi] = MFMA(aH[m], bH, acc[o][m][nfi]);
                    acc[o][m][nfi] = MFMA(aL[m], bH, acc[o][m][nfi]);
                }
            }
        }
    }

#pragma unroll
    for (int o = 0; o < 2; ++o) {
        ushort* Yo = Y + (size_t)(2 * y + o) * ((size_t)NN * 128);
#pragma unroll
        for (int m = 0; m < 2; ++m)
#pragma unroll
            for (int nfi = 0; nfi < 2; ++nfi) {
                int c = (np * 2 + nfi) * 16 + l15;
#pragma unroll
                for (int i = 0; i < 4; ++i) {
                    int gr = row0 + rh * 32 + m * 16 + lh * 4 + i;
                    if (gr < NN) Yo[(size_t)gr * 128 + c] = f2bf1(acc[o][m][nfi][i]);
                }
            }
    }
}

// ---------------- merged dual gather, 16-lane row groups (4 rows/wave, high MLP) ----------------
// out[d] = rsdA*sum(scl*YA[s]) + rsdB*sum(scl*YB[s]) + bA + bB
// lane sub = tid&15 owns 16 B (8 bf16 cols) of the row: cols sub*8 .. sub*8+7.
template <bool OUT_BF16>
__global__ __launch_bounds__(256) void gather4_kernel(GPair g0, GPair g1,
                                                      uint* __restrict__ ob0, uint* __restrict__ ob1,
                                                      float* __restrict__ of0, float* __restrict__ of1) {
    const GPair G = blockIdx.y ? g1 : g0;
    const int tid = threadIdx.x;
    const int d = blockIdx.x * 16 + (tid >> 4);
    const int sub = tid & 15;

    float aA[8], aB[8];
#pragma unroll
    for (int k = 0; k < 8; k++) { aA[k] = 0.f; aB[k] = 0.f; }

    auto acc8 = [&](float* a, const ushort* Y, int s, float sc) {
        ui32x4 u = ((const ui32x4*)(Y + (size_t)s * 128))[sub];
#pragma unroll
        for (int t = 0; t < 4; ++t) {
            a[2 * t + 0] = fmaf(__uint_as_float(u[t] << 16), sc, a[2 * t + 0]);
            a[2 * t + 1] = fmaf(__uint_as_float(u[t] & 0xffff0000u), sc, a[2 * t + 1]);
        }
    };

    {
        int j0 = G.rpA[d], j1 = G.rpA[d + 1];
        int j = j0;
        for (; j + 2 <= j1; j += 2) {
            int2 e0 = G.eA[j], e1 = G.eA[j + 1];
            acc8(aA, G.YA, e0.x, __int_as_float(e0.y));
            acc8(aA, G.YA, e1.x, __int_as_float(e1.y));
        }
        if (j < j1) {
            int2 e0 = G.eA[j];
            acc8(aA, G.YA, e0.x, __int_as_float(e0.y));
        }
    }
    {
        int j0 = G.rpB[d], j1 = G.rpB[d + 1];
        int j = j0;
        for (; j + 2 <= j1; j += 2) {
            int2 e0 = G.eB[j], e1 = G.eB[j + 1];
            acc8(aB, G.YB, e0.x, __int_as_float(e0.y));
            acc8(aB, G.YB, e1.x, __int_as_float(e1.y));
        }
        if (j < j1) {
            int2 e0 = G.eB[j];
            acc8(aB, G.YB, e0.x, __int_as_float(e0.y));
        }
    }

    float rA = G.rsdA[d], rB = G.rsdB[d];
    int c = sub * 8;
    float v[8];
#pragma unroll
    for (int k = 0; k < 8; ++k)
        v[k] = fmaf(aA[k], rA, fmaf(aB[k], rB, G.bA[c + k] + G.bB[c + k]));

    if (OUT_BF16) {
        uint* o = blockIdx.y ? ob1 : ob0;
        uint4 w;
        w.x = pk_bf16(v[0], v[1]); w.y = pk_bf16(v[2], v[3]);
        w.z = pk_bf16(v[4], v[5]); w.w = pk_bf16(v[6], v[7]);
        ((uint4*)o)[(size_t)d * 16 + sub] = w;
    } else {
        float* o = blockIdx.y ? of1 : of0;
        f32x4 w0 = {v[0], v[1], v[2], v[3]};
        f32x4 w1 = {v[4], v[5], v[6], v[7]};
        *reinterpret_cast<f32x4*>(o + (size_t)d * 128 + c) = w0;
        *reinterpret_cast<f32x4*>(o + (size_t)d * 128 + c + 4) = w1;
    }
}

// ---------------- GRU + layer-2 transform: h = gru(relu(hcpre)); Z[2y+o] = h @ W2[2y+o] ----------------
__global__ __launch_bounds__(512) void gruz_kernel(
    const ushort* __restrict__ hcpre,
    const ushort* __restrict__ pk_h,
    const float* __restrict__ bih, const float* __restrict__ bhh,
    ushort* __restrict__ Z) {
    __shared__ __align__(16) ushort Xh[64 * 128];
    __shared__ __align__(16) ushort Hh[64 * 128];
    const int y = blockIdx.y;
    const ushort* xs = hcpre + (size_t)y * NU * 128;
    const int tid = threadIdx.x;
    const int row0 = blockIdx.x * 64;

    // ---- stage relu(x): x already bf16 -> exact staging (relu via sign test) ----
    {
        const int r = tid >> 3, q = tid & 7;
        const int gr = row0 + r;
        const ui32x4* xp = (const ui32x4*)(xs + (size_t)gr * 128 + q * 16);
#pragma unroll
        for (int k = 0; k < 2; ++k) {
            ui32x4 v = (gr < NN) ? xp[k] : (ui32x4)(0u);
#pragma unroll
            for (int t = 0; t < 4; ++t) {
                uint u = v[t];
                uint lo = (u & 0x8000u) ? 0u : (u & 0xFFFFu);
                uint hi = (u & 0x80000000u) ? 0u : (u & 0xFFFF0000u);
                v[t] = lo | hi;
            }
            int base = (r * 128 + q * 16 + k * 8) ^ ((r & 7) << 3);
            *reinterpret_cast<ui32x4*>(&Xh[base]) = v;
        }
    }
    __syncthreads();

    const int wv = tid >> 6, l = tid & 63;
    const int l15 = l & 15, lh = l >> 4;
    const int rh = wv >> 2, np = wv & 3;
    const ushort* gwh = pk_h + (size_t)8 * 16384;

    // ---- GRU gates GEMM: gi = x @ wih^T ----
    f32x4 g3[3][2][2];
#pragma unroll
    for (int g = 0; g < 3; g++)
#pragma unroll
        for (int m = 0; m < 2; m++)
#pragma unroll
            for (int nfi = 0; nfi < 2; nfi++) g3[g][m][nfi] = (f32x4)(0.f);

#pragma unroll
    for (int ks = 0; ks < 4; ++ks) {
        bf16x8 aH[2];
#pragma unroll
        for (int m = 0; m < 2; ++m) {
            int row = rh * 32 + m * 16 + l15;
            int idx = (row * 128 + ks * 32 + lh * 8) ^ ((row & 7) << 3);
            aH[m] = *reinterpret_cast<const bf16x8*>(&Xh[idx]);
        }
#pragma unroll
        for (int g = 0; g < 3; ++g) {
#pragma unroll
            for (int nfi = 0; nfi < 2; ++nfi) {
                int gnf = g * 8 + np * 2 + nfi;
                size_t off = ((size_t)(gnf * 4 + ks) * 64 + l) * 8;
                bf16x8 bH = *reinterpret_cast<const bf16x8*>(gwh + off);
#pragma unroll
                for (int m = 0; m < 2; ++m)
                    g3[g][m][nfi] = MFMA(aH[m], bH, g3[g][m][nfi]);
            }
        }
    }

    // ---- gates (gh = bhh, h0 = 0); stage h bf16 into Hh (cvt_pk, biases hoisted) ----
#pragma unroll
    for (int nfi = 0; nfi < 2; ++nfi) {
        int c = (np * 2 + nfi) * 16 + l15;
        float b0 = bih[c] + bhh[c];
        float b1 = bih[128 + c] + bhh[128 + c];
        float b2i = bih[256 + c], b2h = bhh[256 + c];
#pragma unroll
        for (int m = 0; m < 2; ++m) {
#pragma unroll
            for (int i = 0; i < 4; ++i) {
                int rr = rh * 32 + m * 16 + lh * 4 + i;
                float rg = fsig(g3[0][m][nfi][i] + b0);
                float zz = fsig(g3[1][m][nfi][i] + b1);
                float nn = ftanh(g3[2][m][nfi][i] + b2i + rg * b2h);
                Hh[(rr * 128 + c) ^ ((rr & 7) << 3)] = f2bf1((1.f - zz) * nn);
            }
        }
    }
    __syncthreads();

    // ---- Z GEMMs: Z[2y+o] = h @ W2[2y+o] ----
    f32x4 za[2][2][2];
#pragma unroll
    for (int o = 0; o < 2; o++)
#pragma unroll
        for (int m = 0; m < 2; m++)
#pragma unroll
            for (int nfi = 0; nfi < 2; nfi++) za[o][m][nfi] = (f32x4)(0.f);

#pragma unroll
    for (int ks = 0; ks < 4; ++ks) {
        bf16x8 aH[2];
#pragma unroll
        for (int m = 0; m < 2; ++m) {
            int row = rh * 32 + m * 16 + l15;
            int idx = (row * 128 + ks * 32 + lh * 8) ^ ((row & 7) << 3);
            aH[m] = *reinterpret_cast<const bf16x8*>(&Hh[idx]);
        }
#pragma unroll
        for (int o = 0; o < 2; ++o) {
            const ushort* wh = pk_h + (size_t)(4 + 2 * y + o) * 16384;
#pragma unroll
            for (int nfi = 0; nfi < 2; ++nfi) {
                int nf = np * 2 + nfi;
                size_t off = ((size_t)(nf * 4 + ks) * 64 + l) * 8;
                bf16x8 bH = *reinterpret_cast<const bf16x8*>(wh + off);
#pragma unroll
                for (int m = 0; m < 2; ++m)
                    za[o][m][nfi] = MFMA(aH[m], bH, za[o][m][nfi]);
            }
        }
    }

#pragma unroll
    for (int o = 0; o < 2; ++o) {
        ushort* Zo = Z + (size_t)(2 * y + o) * ((size_t)NN * 128);
#pragma unroll
        for (int m = 0; m < 2; ++m)
#pragma unroll
            for (int nfi = 0; nfi < 2; ++nfi) {
                int c = (np * 2 + nfi) * 16 + l15;
#pragma unroll
                for (int i = 0; i < 4; ++i) {
                    int gr = row0 + rh * 32 + m * 16 + lh * 4 + i;
                    if (gr < NN) Zo[(size_t)gr * 128 + c] = f2bf1(za[o][m][nfi][i]);
                }
            }
    }
}

// ---------------- launch ----------------
extern "C" void kernel_launch(void* const* d_in, const int* in_sizes, int n_in,
                              void* d_out, int out_size, void* d_ws, size_t ws_size,
                              hipStream_t stream) {
    const float* feat_user = (const float*)d_in[0];
    const float* feat_item = (const float*)d_in[1];

    // relation order: 0=follows(U->U) 1=buys(U->I) 2=revbuys(I->U) 3=similar(I->I)
    Ptr4 srcs = {{(const int*)d_in[3], (const int*)d_in[9], (const int*)d_in[15], (const int*)d_in[21]}};
    Ptr4 dsts = {{(const int*)d_in[4], (const int*)d_in[10], (const int*)d_in[16], (const int*)d_in[22]}};
    const float* b1[4] = {(const float*)d_in[6],  (const float*)d_in[12], (const float*)d_in[18], (const float*)d_in[24]};
    const float* b2[4] = {(const float*)d_in[8],  (const float*)d_in[14], (const float*)d_in[20], (const float*)d_in[26]};

    PackW pw = {{(const float*)d_in[5], (const float*)d_in[11], (const float*)d_in[17], (const float*)d_in[23],
                 (const float*)d_in[7], (const float*)d_in[13], (const float*)d_in[19], (const float*)d_in[25],
                 (const float*)d_in[27]}};
    const float* bih = (const float*)d_in[29];
    const float* bhh = (const float*)d_in[30];

    // ---- workspace ----
    char* w = (char*)d_ws;
    auto alloc = [&](size_t bytes) { char* r = w; w += (bytes + 255) & ~(size_t)255; return r; };
    int* cnt8         = (int*)alloc(8 * NN * sizeof(int));
    float* rs_dst_all = (float*)alloc(4 * NN * sizeof(float));
    int* row_ptr_all  = (int*)alloc(4 * (NN + 1) * sizeof(int));
    int2* edge_all    = (int2*)alloc((size_t)4 * NE * sizeof(int2));
    int* part         = (int*)alloc(4 * 128 * sizeof(int));
    ushort* pkh_all   = (ushort*)alloc((size_t)(8 * 16384 + 49152) * sizeof(ushort));
    ushort* Ybuf      = (ushort*)alloc((size_t)4 * NN * 128 * sizeof(ushort));  // Y then Z (reused)

    float* outLo = (float*)d_out;
    float* outHi = outLo + (size_t)NU * 128;
    ushort* hcpre = (ushort*)d_out;          // bf16 scratch in d_out (overwritten by final gathers)

    const int EB = (NE + 255) / 256;

    // ---- CSR build ----
    hipMemsetAsync(cnt8, 0, 8 * NN * sizeof(int), stream);
    hist8_kernel<<<dim3(EB, 8), 256, 0, stream>>>(srcs, dsts, cnt8);
    scan_phase_a<<<dim3(NB_SCAN, 4), 256, 0, stream>>>(cnt8, part);
    scan_phase_b<<<4, 128, 0, stream>>>(part);
    scan_phase_c<<<dim3(NB_SCAN, 4), 256, 0, stream>>>(cnt8, part, row_ptr_all, rs_dst_all);
    fill4_kernel<<<dim3(EB, 4), 256, 0, stream>>>(srcs, dsts, cnt8, cnt8 + 4 * NN, edge_all);

    // ---- pack weights ----
    pack_all_kernel<<<(8 * 16384 + 49152 + 255) / 256, 256, 0, stream>>>(pw, pkh_all);

    const int GB = (NN + 63) / 64;   // 1563
    const int GGB = NN / 16;         // 6250 (16 rows/block, 16-lane groups)

    auto RP = [&](int r) { return row_ptr_all + r * (NN + 1); };
    auto EG = [&](int r) { return edge_all + (size_t)r * NE; };
    auto RD = [&](int r) { return rs_dst_all + r * NN; };
    auto YS = [&](int s) { return (const ushort*)(Ybuf + (size_t)s * NN * 128); };

    // ---- layer-1 transform: Y[0]=fu@W1f Y[1]=fu@W1b Y[2]=fi@W1r Y[3]=fi@W1s ----
    transform_kernel<<<dim3(GB, 2), 512, 0, stream>>>(feat_user, feat_item, pkh_all, Ybuf);

    // ---- layer-1 gathers (merged) -> hc_pre (bf16, in d_out scratch) ----
    {
        GPair gy0 = {YS(0), YS(2), RP(0), EG(0), RD(0), RP(2), EG(2), RD(2), b1[0], b1[2]};
        GPair gy1 = {YS(1), YS(3), RP(1), EG(1), RD(1), RP(3), EG(3), RD(3), b1[1], b1[3]};
        gather4_kernel<true><<<dim3(GGB, 2), 256, 0, stream>>>(
            gy0, gy1, (uint*)hcpre, (uint*)(hcpre + (size_t)NU * 128), nullptr, nullptr);
    }

    // ---- GRU + layer-2 transform: Z[0]=hu@W2f Z[1]=hu@W2b Z[2]=hi@W2r Z[3]=hi@W2s ----
    gruz_kernel<<<dim3(GB, 2), 512, 0, stream>>>(hcpre, pkh_all, bih, bhh, Ybuf);

    // ---- layer-2 gathers (merged) -> d_out (fp32) ----
    {
        GPair gy0 = {YS(0), YS(2), RP(0), EG(0), RD(0), RP(2), EG(2), RD(2), b2[0], b2[2]};
        GPair gy1 = {YS(1), YS(3), RP(1), EG(1), RD(1), RP(3), EG(3), RD(3), b2[1], b2[3]};
        gather4_kernel<false><<<dim3(GGB, 2), 256, 0, stream>>>(
            gy0, gy1, nullptr, nullptr, outLo, outHi);
    }
}